// Round 17
// baseline (131.460 us; speedup 1.0000x reference)
//
#include <hip/hip_runtime.h>
#include <hip/hip_bf16.h>

#define N_LIG 100000
#define N_TGT 4000
#define NEDGE 150000
#define DT 1280
#define HD 128
#define CAP_L 32
#define CAP_T 128
#define NTILE_L 6250            // N_LIG / 16
#define NTILE_PAD 6252
#define PL_BLOCKS 1563          // ceil(NTILE_L/4)

typedef __attribute__((ext_vector_type(8))) short short8v;
typedef __attribute__((ext_vector_type(4))) float f32x4;

static __device__ __forceinline__ ushort f2bf(float f) {
    __hip_bfloat16 h = __float2bfloat16(f);
    union { __hip_bfloat16 h; ushort u; } c; c.h = h; return c.u;
}
static __device__ __forceinline__ float bf2f(ushort u) {
    union { unsigned v; float f; } c; c.v = ((unsigned)u) << 16; return c.f;
}

// ---------------------------------------------------------------------------
// K0: merged prep — fragment packing for all MFMA operands + counter zeroing.
// ---------------------------------------------------------------------------
__global__ __launch_bounds__(256) void k_pack(
    const float* __restrict__ W2, uint4* __restrict__ Wf,
    const float* __restrict__ Wr, const float* __restrict__ Wl,
    uint4* __restrict__ Wf1,
    const float* __restrict__ xt, uint4* __restrict__ xtf,
    int4* __restrict__ cntz,
    const float* __restrict__ W2a, const float* __restrict__ W2b,
    uint4* __restrict__ Wf2)
{
    int bx = blockIdx.x;
    if (bx < 8) {
        int gid = bx * 256 + threadIdx.x;           // 2048
        int lane = gid & 63, frag = gid >> 6;       // frag 0..31
        int ks = frag >> 3, ct = frag & 7;
        int l15 = lane & 15, g = lane >> 4;
        int k = ks * 32 + g * 4, n = ct * 16 + l15;
        union { ushort us[8]; uint4 u; } o;
#pragma unroll
        for (int j = 0; j < 4; ++j) {
            o.us[j]     = f2bf(W2[(size_t)(k + j) * HD + n]);
            o.us[4 + j] = f2bf(W2[(size_t)(k + 16 + j) * HD + n]);
        }
        Wf[gid] = o.u;
    } else if (bx < 168) {
        int gid = (bx - 8) * 256 + threadIdx.x;     // 40960
        int lane = gid & 63, frag = gid >> 6;       // 0..639
        int ks = frag >> 4, nct = frag & 15;
        int l15 = lane & 15, g = lane >> 4;
        int k = ks * 32 + g * 4, n = nct * 16 + l15;
        const float* Ws = (n < HD) ? Wr : Wl;
        int nn = n & 127;
        union { ushort us[8]; uint4 u; } o;
#pragma unroll
        for (int j = 0; j < 4; ++j) {
            o.us[j]     = f2bf(Ws[(size_t)(k + j) * HD + nn]);
            o.us[4 + j] = f2bf(Ws[(size_t)(k + 16 + j) * HD + nn]);
        }
        Wf1[gid] = o.u;
    } else if (bx < 2668) {
        int gid = (bx - 168) * 256 + threadIdx.x;   // 640000
        int lane = gid & 63, frag = gid >> 6;       // 0..9999
        int ks = frag % 40, rt = frag / 40;
        int row = rt * 16 + (lane & 15);
        int kb = ks * 32 + (lane >> 4) * 4;
        float4 a0 = *reinterpret_cast<const float4*>(xt + (size_t)row * DT + kb);
        float4 a1 = *reinterpret_cast<const float4*>(xt + (size_t)row * DT + kb + 16);
        union { ushort us[8]; uint4 u; } o;
        o.us[0] = f2bf(a0.x); o.us[1] = f2bf(a0.y); o.us[2] = f2bf(a0.z); o.us[3] = f2bf(a0.w);
        o.us[4] = f2bf(a1.x); o.us[5] = f2bf(a1.y); o.us[6] = f2bf(a1.z); o.us[7] = f2bf(a1.w);
        xtf[gid] = o.u;
    } else if (bx < 2770) {
        int i = (bx - 2668) * 256 + threadIdx.x;
        if (i < 26000) cntz[i] = make_int4(0, 0, 0, 0);
    } else {
        int gid = (bx - 2770) * 256 + threadIdx.x;  // 4096
        int lane = gid & 63, frag = gid >> 6;       // 0..63
        int ks = frag >> 4, nct = frag & 15;
        int l15 = lane & 15, g = lane >> 4;
        int k = ks * 32 + g * 4, n = nct * 16 + l15;
        const float* Ws = (n < HD) ? W2a : W2b;
        int nn = n & 127;
        union { ushort us[8]; uint4 u; } o;
#pragma unroll
        for (int j = 0; j < 4; ++j) {
            o.us[j]     = f2bf(Ws[(size_t)(k + j) * HD + nn]);
            o.us[4 + j] = f2bf(Ws[(size_t)(k + 16 + j) * HD + nn]);
        }
        Wf2[gid] = o.u;
    }
}

// ---------------------------------------------------------------------------
// K1: build adjacency buckets (int atomics only).
// ---------------------------------------------------------------------------
__global__ __launch_bounds__(256) void k_fill(
    const int* __restrict__ src, const int* __restrict__ dst,
    int* __restrict__ cnt_src, int* __restrict__ cnt_dst,
    int* __restrict__ bsrc, int* __restrict__ bdst)
{
    int e = blockIdx.x * 256 + threadIdx.x;
    if (e >= NEDGE) return;
    int s = src[e], d = dst[e];
    int ps = atomicAdd(&cnt_src[s], 1);
    if (ps < CAP_L) bsrc[(size_t)s * CAP_L + ps] = d;
    int pd = atomicAdd(&cnt_dst[d], 1);
    if (pd < CAP_T) bdst[(size_t)d * CAP_T + pd] = s;
}

// ---------------------------------------------------------------------------
// K2: fused target pipeline, 512 threads (8 waves).
// ---------------------------------------------------------------------------
__global__ __launch_bounds__(512) void k_tgt1m(
    const uint4* __restrict__ xtf,    // [250*40][64] bf16 A-frags
    const uint4* __restrict__ Wf1,    // [640][64] bf16 B-frags
    const uint4* __restrict__ Wf2,    // [64][64] bf16 B-frags (conv2)
    const float* __restrict__ xl,
    const int* __restrict__ bdst, const int* __restrict__ cnt_dst,
    const float* __restrict__ W1lt_l, // [4,128]
    const float* __restrict__ b1lt,
    float* __restrict__ y_t1,
    float* __restrict__ y_t2, float* __restrict__ htW2r)
{
    __shared__ float  ms[16][4];
    __shared__ ushort hts[16][136];

    int w = threadIdx.x >> 6;         // 0..7
    int lane = threadIdx.x & 63;
    int l15 = lane & 15, g = lane >> 4;
    int rt = blockIdx.x;
    int row0 = rt * 16;

    // phase A: neighbor mean of x_l
    if (threadIdx.x < 128) {
        int r = threadIdx.x >> 3, lane8 = threadIdx.x & 7;
        int row = row0 + r;
        int deg = cnt_dst[row];
        int n = min(deg, CAP_T);
        float4 acc = make_float4(0.f, 0.f, 0.f, 0.f);
        for (int i = lane8; i < n; i += 8) {
            int sid = bdst[(size_t)row * CAP_T + i];
            float4 x = *reinterpret_cast<const float4*>(xl + 4ull * (unsigned)sid);
            acc.x += x.x; acc.y += x.y; acc.z += x.z; acc.w += x.w;
        }
#pragma unroll
        for (int off = 1; off < 8; off <<= 1) {
            acc.x += __shfl_xor(acc.x, off); acc.y += __shfl_xor(acc.y, off);
            acc.z += __shfl_xor(acc.z, off); acc.w += __shfl_xor(acc.w, off);
        }
        if (lane8 == 0) {
            float dinv = 1.0f / fmaxf((float)deg, 1.0f);
            ms[r][0] = acc.x * dinv; ms[r][1] = acc.y * dinv;
            ms[r][2] = acc.z * dinv; ms[r][3] = acc.w * dinv;
        }
    }

    // phase B: conv1 MFMA K-loop
    f32x4 acc[2];
#pragma unroll
    for (int ct = 0; ct < 2; ++ct) acc[ct] = (f32x4){0.f, 0.f, 0.f, 0.f};

    for (int ks = 0; ks < DT / 32; ++ks) {
        union { uint4 u; short8v s; } ua;
        ua.u = xtf[(size_t)(rt * 40 + ks) * 64 + lane];
#pragma unroll
        for (int ct = 0; ct < 2; ++ct) {
            union { uint4 u; short8v s; } ub;
            ub.u = Wf1[(size_t)(ks * 16 + w * 2 + ct) * 64 + lane];
            acc[ct] = __builtin_amdgcn_mfma_f32_16x16x32_bf16(ua.s, ub.s, acc[ct], 0, 0, 0);
        }
    }

    __syncthreads();

    // phase C: h_t -> LDS bf16 (waves 0-3); y_t1 -> global (waves 4-7)
    if (w < 4) {
#pragma unroll
        for (int ct = 0; ct < 2; ++ct) {
            int c = w * 32 + ct * 16 + l15;
            float wl0 = W1lt_l[c], wl1 = W1lt_l[HD + c],
                  wl2 = W1lt_l[2 * HD + c], wl3 = W1lt_l[3 * HD + c];
            float bb = b1lt[c];
#pragma unroll
            for (int j = 0; j < 4; ++j) {
                int r = 4 * g + j;
                float v = acc[ct][j] + bb + ms[r][0] * wl0 + ms[r][1] * wl1
                        + ms[r][2] * wl2 + ms[r][3] * wl3;
                hts[r][c] = f2bf(fmaxf(v, 0.0f));
            }
        }
    } else {
#pragma unroll
        for (int ct = 0; ct < 2; ++ct) {
            int c = (w - 4) * 32 + ct * 16 + l15;
#pragma unroll
            for (int j = 0; j < 4; ++j) {
                int grow = row0 + 4 * g + j;
                y_t1[(size_t)grow * HD + c] = acc[ct][j];
            }
        }
    }
    __syncthreads();

    // phase D: conv2 MFMA (K=128) from LDS h_t
    f32x4 acc2[2];
#pragma unroll
    for (int ct = 0; ct < 2; ++ct) acc2[ct] = (f32x4){0.f, 0.f, 0.f, 0.f};

#pragma unroll
    for (int ks2 = 0; ks2 < 4; ++ks2) {
        int kb2 = ks2 * 32 + g * 4;
        union { ushort us[8]; short8v s; } ua2;
        *reinterpret_cast<ushort4*>(&ua2.us[0]) =
            *reinterpret_cast<const ushort4*>(&hts[l15][kb2]);
        *reinterpret_cast<ushort4*>(&ua2.us[4]) =
            *reinterpret_cast<const ushort4*>(&hts[l15][kb2 + 16]);
#pragma unroll
        for (int ct = 0; ct < 2; ++ct) {
            union { uint4 u; short8v s; } ub2;
            ub2.u = Wf2[(size_t)(ks2 * 16 + w * 2 + ct) * 64 + lane];
            acc2[ct] = __builtin_amdgcn_mfma_f32_16x16x32_bf16(ua2.s, ub2.s, acc2[ct], 0, 0, 0);
        }
    }

    float* outp = (w < 4) ? y_t2 : htW2r;
    int cw = (w < 4) ? w : (w - 4);
#pragma unroll
    for (int ct = 0; ct < 2; ++ct) {
        int c = cw * 32 + ct * 16 + l15;
#pragma unroll
        for (int j = 0; j < 4; ++j) {
            int grow = row0 + 4 * g + j;
            outp[(size_t)grow * HD + c] = acc2[ct][j];
        }
    }
}

// ---------------------------------------------------------------------------
// K3: fused ligand conv1. 32 threads/node (8 nodes/block):
//   tc<16: h_l chunk from y_t1 -> hlb (CHUNK-ordered row, one uint4) + hlbf
//   tc>=16: gl2 chunk from y_t2 -> gl2 (CHUNK-ordered row, one uint4)
// Chunk tc holds columns ks*32+g*4+{0..3} and +16..+19 (ks=tc>>2, g=tc&3).
// All stores are full contiguous 16B -> no partial-line RMW.
// ---------------------------------------------------------------------------
__global__ __launch_bounds__(256) void k_hl(
    const float* __restrict__ xl,
    const float* __restrict__ y_t1, const float* __restrict__ y_t2,
    const int* __restrict__ bsrc, const int* __restrict__ cnt_src,
    const float* __restrict__ W1tl_r,  // [4,128]
    const float* __restrict__ b1tl,
    uint4* __restrict__ hlb,   // [N_LIG][16] chunk-ordered
    uint4* __restrict__ hlbf,  // fragment layout
    uint4* __restrict__ gl2)   // [N_LIG][16] chunk-ordered
{
    int tc32 = threadIdx.x & 31;
    int node = blockIdx.x * 8 + (threadIdx.x >> 5);
    int part = tc32 >> 4;            // 0: h_l, 1: gl2
    int tc = tc32 & 15;
    int ks = tc >> 2, g = tc & 3;
    int kb = ks * 32 + g * 4;

    int deg = cnt_src[node];
    int n = min(deg, CAP_L);
    const float* ysrc = part ? y_t2 : y_t1;

    float4 s0 = make_float4(0.f, 0.f, 0.f, 0.f);
    float4 s1 = make_float4(0.f, 0.f, 0.f, 0.f);
    for (int i = 0; i < n; ++i) {
        int did = bsrc[(size_t)node * CAP_L + i];
        float4 v0 = *reinterpret_cast<const float4*>(ysrc + (size_t)did * HD + kb);
        float4 v1 = *reinterpret_cast<const float4*>(ysrc + (size_t)did * HD + kb + 16);
        s0.x += v0.x; s0.y += v0.y; s0.z += v0.z; s0.w += v0.w;
        s1.x += v1.x; s1.y += v1.y; s1.z += v1.z; s1.w += v1.w;
    }
    float dinv = 1.0f / fmaxf((float)deg, 1.0f);

    union { ushort us[8]; uint4 u; } o;
    if (part == 0) {
        float4 x = *reinterpret_cast<const float4*>(xl + 4ull * (unsigned)node);
        float4 b0 = *reinterpret_cast<const float4*>(b1tl + kb);
        float4 b1 = *reinterpret_cast<const float4*>(b1tl + kb + 16);
        float4 wa0 = *reinterpret_cast<const float4*>(W1tl_r + 0 * HD + kb);
        float4 wa1 = *reinterpret_cast<const float4*>(W1tl_r + 1 * HD + kb);
        float4 wa2 = *reinterpret_cast<const float4*>(W1tl_r + 2 * HD + kb);
        float4 wa3 = *reinterpret_cast<const float4*>(W1tl_r + 3 * HD + kb);
        float4 wb0 = *reinterpret_cast<const float4*>(W1tl_r + 0 * HD + kb + 16);
        float4 wb1 = *reinterpret_cast<const float4*>(W1tl_r + 1 * HD + kb + 16);
        float4 wb2 = *reinterpret_cast<const float4*>(W1tl_r + 2 * HD + kb + 16);
        float4 wb3 = *reinterpret_cast<const float4*>(W1tl_r + 3 * HD + kb + 16);

        o.us[0] = f2bf(fmaxf(s0.x * dinv + b0.x + x.x * wa0.x + x.y * wa1.x + x.z * wa2.x + x.w * wa3.x, 0.f));
        o.us[1] = f2bf(fmaxf(s0.y * dinv + b0.y + x.x * wa0.y + x.y * wa1.y + x.z * wa2.y + x.w * wa3.y, 0.f));
        o.us[2] = f2bf(fmaxf(s0.z * dinv + b0.z + x.x * wa0.z + x.y * wa1.z + x.z * wa2.z + x.w * wa3.z, 0.f));
        o.us[3] = f2bf(fmaxf(s0.w * dinv + b0.w + x.x * wa0.w + x.y * wa1.w + x.z * wa2.w + x.w * wa3.w, 0.f));
        o.us[4] = f2bf(fmaxf(s1.x * dinv + b1.x + x.x * wb0.x + x.y * wb1.x + x.z * wb2.x + x.w * wb3.x, 0.f));
        o.us[5] = f2bf(fmaxf(s1.y * dinv + b1.y + x.x * wb0.y + x.y * wb1.y + x.z * wb2.y + x.w * wb3.y, 0.f));
        o.us[6] = f2bf(fmaxf(s1.z * dinv + b1.z + x.x * wb0.z + x.y * wb1.z + x.z * wb2.z + x.w * wb3.z, 0.f));
        o.us[7] = f2bf(fmaxf(s1.w * dinv + b1.w + x.x * wb0.w + x.y * wb1.w + x.z * wb2.w + x.w * wb3.w, 0.f));

        hlb[(size_t)node * 16 + tc] = o.u;
        int lane = (node & 15) + 16 * g;
        hlbf[(size_t)((node >> 4) * 4 + ks) * 64 + lane] = o.u;
    } else {
        o.us[0] = f2bf(s0.x * dinv); o.us[1] = f2bf(s0.y * dinv);
        o.us[2] = f2bf(s0.z * dinv); o.us[3] = f2bf(s0.w * dinv);
        o.us[4] = f2bf(s1.x * dinv); o.us[5] = f2bf(s1.y * dinv);
        o.us[6] = f2bf(s1.z * dinv); o.us[7] = f2bf(s1.w * dinv);
        gl2[(size_t)node * 16 + tc] = o.u;
    }
}

// ---------------------------------------------------------------------------
// K5+K6 merged predictors (256 threads).
//   blockIdx < N_TGT: target row — LDS-staged indices, 16x16 uint4 gather
//     from chunk-ordered hlb, un-permute in msh phase (round-11 verified).
//   else: ligand MFMA predictor, chunk-offset gl2 epilogue.
// ---------------------------------------------------------------------------
__global__ __launch_bounds__(256) void k_ptl(
    const uint4* __restrict__ hlb,    // chunk-ordered
    const uint4* __restrict__ hlbf,
    const uint4* __restrict__ Wf,
    const ushort* __restrict__ gl2,   // chunk-ordered (read as scalars)
    const int* __restrict__ bdst, const int* __restrict__ cnt_dst,
    const float* __restrict__ Wlt,    // W2lt_l [128,128]
    const float* __restrict__ b2lt,
    const float* __restrict__ b2tl,
    const float* __restrict__ htW2r,
    const float* __restrict__ Wp,     // [256]
    float* __restrict__ p_t, float* __restrict__ p_l)
{
    __shared__ int   idx[CAP_T];
    __shared__ float sm[16][132];
    __shared__ float msh[HD];
    __shared__ float sum2[2];

    if (blockIdx.x < N_TGT) {
        int row = blockIdx.x;
        int deg = cnt_dst[row];
        int nn = min(deg, CAP_T);

        if (threadIdx.x < CAP_T) idx[threadIdx.x] = bdst[(size_t)row * CAP_T + threadIdx.x];
        __syncthreads();

        // 16 groups x 16 lanes; lane loads chunk l16 (16B)
        int wg = threadIdx.x >> 4, l16 = threadIdx.x & 15;
        float s[8];
#pragma unroll
        for (int j = 0; j < 8; ++j) s[j] = 0.f;
        for (int i = wg; i < nn; i += 16) {
            int sid = idx[i];
            union { uint4 u; ushort us[8]; } v;
            v.u = hlb[(size_t)sid * 16 + l16];
#pragma unroll
            for (int j = 0; j < 8; ++j) s[j] += bf2f(v.us[j]);
        }
#pragma unroll
        for (int j = 0; j < 8; ++j) sm[wg][l16 * 8 + j] = s[j];
        __syncthreads();

        if (threadIdx.x < HD) {
            int h = threadIdx.x;
            int tc2 = h >> 3, jj = h & 7;
            float dinv = 1.0f / fmaxf((float)deg, 1.0f);
            float acc = 0.f;
#pragma unroll
            for (int w2 = 0; w2 < 16; ++w2) acc += sm[w2][tc2 * 8 + jj];
            // chunk tc2=(ks,g): us[jj] -> col = ks*32 + (jj>=4)*16 + g*4 + (jj&3)
            int ks2 = tc2 >> 2, g2 = tc2 & 3;
            int col = ks2 * 32 + ((jj >> 2) << 4) + g2 * 4 + (jj & 3);
            msh[col] = acc * dinv;
        }
        __syncthreads();

        if (threadIdx.x < HD) {
            int h = threadIdx.x;
            float g = 0.f;
            for (int k = 0; k < HD; k += 4) {
                float4 mk = *reinterpret_cast<const float4*>(&msh[k]);
                g += mk.x * Wlt[(size_t)(k + 0) * HD + h] + mk.y * Wlt[(size_t)(k + 1) * HD + h]
                   + mk.z * Wlt[(size_t)(k + 2) * HD + h] + mk.w * Wlt[(size_t)(k + 3) * HD + h];
            }
            float v = fmaxf(g + b2lt[h] + htW2r[(size_t)row * HD + h], 0.0f);
            float part = v * Wp[HD + h];
#pragma unroll
            for (int off = 1; off < 64; off <<= 1) part += __shfl_xor(part, off);
            if ((h & 63) == 0) sum2[h >> 6] = part;
        }
        __syncthreads();
        if (threadIdx.x == 0) p_t[row] = sum2[0] + sum2[1];
        return;
    }

    // ---- ligand branch: 4 tiles/block, pure streaming ----
    int wid = threadIdx.x >> 6;
    int lane = threadIdx.x & 63;
    int l15 = lane & 15, g = lane >> 4;
    int tile = (blockIdx.x - N_TGT) * 4 + wid;
    int wrow0 = tile * 16;

    f32x4 acc[8];
#pragma unroll
    for (int ct = 0; ct < 8; ++ct) acc[ct] = (f32x4){0.f, 0.f, 0.f, 0.f};

#pragma unroll
    for (int ks = 0; ks < 4; ++ks) {
        union { uint4 u; short8v s; } ua;
        ua.u = hlbf[(size_t)(tile * 4 + ks) * 64 + lane];
#pragma unroll
        for (int ct = 0; ct < 8; ++ct) {
            union { uint4 u; short8v s; } ub;
            ub.u = Wf[(ks * 8 + ct) * 64 + lane];
            acc[ct] = __builtin_amdgcn_mfma_f32_16x16x32_bf16(ua.s, ub.s, acc[ct], 0, 0, 0);
        }
    }

    float wpv[8], bv[8];
    int off8[8];
#pragma unroll
    for (int ct = 0; ct < 8; ++ct) {
        int c = ct * 16 + l15;
        wpv[ct] = Wp[c];
        bv[ct]  = b2tl[c];
        // col c -> chunk-ordered pos: chunk=(c>>5)*4+((c&15)>>2), elem=((c>>4)&1)*4+(c&3)
        off8[ct] = (((ct >> 1) * 4 + (l15 >> 2)) << 3) + ((ct & 1) << 2) + (l15 & 3);
    }

#pragma unroll
    for (int j = 0; j < 4; ++j) {
        int row = wrow0 + g * 4 + j;
        bool valid = row < N_LIG;
        int lrow = valid ? row : 0;
        const ushort* gp = gl2 + (size_t)lrow * HD;
        float part = 0.f;
#pragma unroll
        for (int ct = 0; ct < 8; ++ct) {
            float v = acc[ct][j] + bf2f(gp[off8[ct]]) + bv[ct];
            part += fmaxf(v, 0.f) * wpv[ct];
        }
#pragma unroll
        for (int off = 1; off < 16; off <<= 1) part += __shfl_xor(part, off);
        if (valid && l15 == 0) p_l[row] = part;
    }
}

// ---------------------------------------------------------------------------
// K7: out[e] = p_l[src[e]] + p_t[dst[e]] + bp
// ---------------------------------------------------------------------------
__global__ __launch_bounds__(256) void k_out(
    const int* __restrict__ src, const int* __restrict__ dst,
    const float* __restrict__ p_l, const float* __restrict__ p_t,
    const float* __restrict__ bp, float* __restrict__ out)
{
    int e = blockIdx.x * 256 + threadIdx.x;
    if (e >= NEDGE) return;
    out[e] = p_l[src[e]] + p_t[dst[e]] + bp[0];
}

// ---------------------------------------------------------------------------
extern "C" void kernel_launch(void* const* d_in, const int* in_sizes, int n_in,
                              void* d_out, int out_size, void* d_ws, size_t ws_size,
                              hipStream_t stream)
{
    const float* x_l    = (const float*)d_in[0];
    const float* x_t    = (const float*)d_in[1];
    const int*   ei     = (const int*)  d_in[2];
    const float* W1lt_l = (const float*)d_in[3];
    const float* b1lt   = (const float*)d_in[4];
    const float* W1lt_r = (const float*)d_in[5];
    const float* W1tl_l = (const float*)d_in[6];
    const float* b1tl   = (const float*)d_in[7];
    const float* W1tl_r = (const float*)d_in[8];
    const float* W2lt_l = (const float*)d_in[9];
    const float* b2lt   = (const float*)d_in[10];
    const float* W2lt_r = (const float*)d_in[11];
    const float* W2tl_l = (const float*)d_in[12];
    const float* b2tl   = (const float*)d_in[13];
    const float* W2tl_r = (const float*)d_in[14];
    const float* Wp     = (const float*)d_in[15];
    const float* bp     = (const float*)d_in[16];

    const int* src = ei;            // ligand indices
    const int* dst = ei + NEDGE;    // target indices

    char* ws = (char*)d_ws;
    size_t o = 0;
    int* cnt_src = (int*)(ws + o); o += (size_t)N_LIG * 4;
    int* cnt_dst = (int*)(ws + o); o += (size_t)N_TGT * 4;
    int* bsrc = (int*)(ws + o); o += (size_t)N_LIG * CAP_L * 4;
    int* bdst = (int*)(ws + o); o += (size_t)N_TGT * CAP_T * 4;
    uint4* hlb   = (uint4*)(ws + o);  o += (size_t)N_LIG * HD * 2;
    uint4* gl2   = (uint4*)(ws + o);  o += (size_t)N_LIG * HD * 2;
    uint4* hlbf  = (uint4*)(ws + o);  o += (size_t)NTILE_PAD * 4 * 64 * 16;
    uint4* Wf    = (uint4*)(ws + o);  o += (size_t)32 * 64 * 16;
    uint4* Wf1   = (uint4*)(ws + o);  o += (size_t)640 * 64 * 16;
    uint4* Wf2   = (uint4*)(ws + o);  o += (size_t)64 * 64 * 16;
    uint4* xtf   = (uint4*)(ws + o);  o += (size_t)10000 * 64 * 16;
    float* y_t1  = (float*)(ws + o); o += (size_t)N_TGT * HD * 4;
    float* y_t2  = (float*)(ws + o); o += (size_t)N_TGT * HD * 4;
    float* htW2r = (float*)(ws + o); o += (size_t)N_TGT * HD * 4;
    float* p_l   = (float*)(ws + o); o += (size_t)N_LIG * 4;
    float* p_t   = (float*)(ws + o); o += (size_t)N_TGT * 4;

    float* out = (float*)d_out;

    // merged prep: fragment packing (incl. conv2 weights) + counter zeroing
    k_pack<<<2786, 256, 0, stream>>>(W2tl_r, Wf, W1lt_r, W1tl_l, Wf1,
                                     x_t, xtf, (int4*)cnt_src,
                                     W2tl_l, W2lt_r, Wf2);

    k_fill<<<(NEDGE + 255) / 256, 256, 0, stream>>>(src, dst, cnt_src, cnt_dst, bsrc, bdst);

    // fused target pipeline: conv1 + neighbor-mean + conv2 projections
    k_tgt1m<<<N_TGT / 16, 512, 0, stream>>>(xtf, Wf1, Wf2, x_l, bdst, cnt_dst,
                                            W1lt_l, b1lt, y_t1, y_t2, htW2r);

    // ligand conv1: 32 threads/node, chunk-ordered outputs, full-line stores
    k_hl<<<N_LIG / 8, 256, 0, stream>>>(x_l, y_t1, y_t2, bsrc, cnt_src,
                                        W1tl_r, b1tl, hlb, hlbf, gl2);

    // merged predictors (target gather-GEMM + ligand MFMA streaming)
    k_ptl<<<N_TGT + PL_BLOCKS, 256, 0, stream>>>(hlb, hlbf, Wf, (const ushort*)gl2,
                                                 bdst, cnt_dst,
                                                 W2lt_l, b2lt, b2tl, htW2r, Wp,
                                                 p_t, p_l);

    // edges
    k_out<<<(NEDGE + 255) / 256, 256, 0, stream>>>(src, dst, p_l, p_t, bp, out);
}

// Round 18
// 107.571 us; speedup vs baseline: 1.2221x; 1.2221x over previous
//
#include <hip/hip_runtime.h>
#include <hip/hip_bf16.h>

#define N_LIG 100000
#define N_TGT 4000
#define NEDGE 150000
#define DT 1280
#define HD 128
#define CAP_L 32
#define CAP_T 128
#define NTILE_L 6250            // N_LIG / 16
#define PL_BLOCKS 1563          // ceil(NTILE_L/4)

typedef __attribute__((ext_vector_type(8))) short short8v;
typedef __attribute__((ext_vector_type(4))) float f32x4;

static __device__ __forceinline__ ushort f2bf(float f) {
    __hip_bfloat16 h = __float2bfloat16(f);
    union { __hip_bfloat16 h; ushort u; } c; c.h = h; return c.u;
}
static __device__ __forceinline__ float bf2f(ushort u) {
    union { unsigned v; float f; } c; c.v = ((unsigned)u) << 16; return c.f;
}

// ---------------------------------------------------------------------------
// K0: merged prep — fragment packing for all MFMA operands + counter zeroing.
// ---------------------------------------------------------------------------
__global__ __launch_bounds__(256) void k_pack(
    const float* __restrict__ W2, uint4* __restrict__ Wf,
    const float* __restrict__ Wr, const float* __restrict__ Wl,
    uint4* __restrict__ Wf1,
    const float* __restrict__ xt, uint4* __restrict__ xtf,
    int4* __restrict__ cntz,
    const float* __restrict__ W2a, const float* __restrict__ W2b,
    uint4* __restrict__ Wf2)
{
    int bx = blockIdx.x;
    if (bx < 8) {
        int gid = bx * 256 + threadIdx.x;           // 2048
        int lane = gid & 63, frag = gid >> 6;       // frag 0..31
        int ks = frag >> 3, ct = frag & 7;
        int l15 = lane & 15, g = lane >> 4;
        int k = ks * 32 + g * 4, n = ct * 16 + l15;
        union { ushort us[8]; uint4 u; } o;
#pragma unroll
        for (int j = 0; j < 4; ++j) {
            o.us[j]     = f2bf(W2[(size_t)(k + j) * HD + n]);
            o.us[4 + j] = f2bf(W2[(size_t)(k + 16 + j) * HD + n]);
        }
        Wf[gid] = o.u;
    } else if (bx < 168) {
        int gid = (bx - 8) * 256 + threadIdx.x;     // 40960
        int lane = gid & 63, frag = gid >> 6;       // 0..639
        int ks = frag >> 4, nct = frag & 15;
        int l15 = lane & 15, g = lane >> 4;
        int k = ks * 32 + g * 4, n = nct * 16 + l15;
        const float* Ws = (n < HD) ? Wr : Wl;
        int nn = n & 127;
        union { ushort us[8]; uint4 u; } o;
#pragma unroll
        for (int j = 0; j < 4; ++j) {
            o.us[j]     = f2bf(Ws[(size_t)(k + j) * HD + nn]);
            o.us[4 + j] = f2bf(Ws[(size_t)(k + 16 + j) * HD + nn]);
        }
        Wf1[gid] = o.u;
    } else if (bx < 2668) {
        int gid = (bx - 168) * 256 + threadIdx.x;   // 640000
        int lane = gid & 63, frag = gid >> 6;       // 0..9999
        int ks = frag % 40, rt = frag / 40;
        int row = rt * 16 + (lane & 15);
        int kb = ks * 32 + (lane >> 4) * 4;
        float4 a0 = *reinterpret_cast<const float4*>(xt + (size_t)row * DT + kb);
        float4 a1 = *reinterpret_cast<const float4*>(xt + (size_t)row * DT + kb + 16);
        union { ushort us[8]; uint4 u; } o;
        o.us[0] = f2bf(a0.x); o.us[1] = f2bf(a0.y); o.us[2] = f2bf(a0.z); o.us[3] = f2bf(a0.w);
        o.us[4] = f2bf(a1.x); o.us[5] = f2bf(a1.y); o.us[6] = f2bf(a1.z); o.us[7] = f2bf(a1.w);
        xtf[gid] = o.u;
    } else if (bx < 2770) {
        int i = (bx - 2668) * 256 + threadIdx.x;
        if (i < 26000) cntz[i] = make_int4(0, 0, 0, 0);
    } else {
        int gid = (bx - 2770) * 256 + threadIdx.x;  // 4096
        int lane = gid & 63, frag = gid >> 6;       // 0..63
        int ks = frag >> 4, nct = frag & 15;
        int l15 = lane & 15, g = lane >> 4;
        int k = ks * 32 + g * 4, n = nct * 16 + l15;
        const float* Ws = (n < HD) ? W2a : W2b;
        int nn = n & 127;
        union { ushort us[8]; uint4 u; } o;
#pragma unroll
        for (int j = 0; j < 4; ++j) {
            o.us[j]     = f2bf(Ws[(size_t)(k + j) * HD + nn]);
            o.us[4 + j] = f2bf(Ws[(size_t)(k + 16 + j) * HD + nn]);
        }
        Wf2[gid] = o.u;
    }
}

// ---------------------------------------------------------------------------
// K1: build adjacency buckets (int atomics only).
// ---------------------------------------------------------------------------
__global__ __launch_bounds__(256) void k_fill(
    const int* __restrict__ src, const int* __restrict__ dst,
    int* __restrict__ cnt_src, int* __restrict__ cnt_dst,
    int* __restrict__ bsrc, int* __restrict__ bdst)
{
    int e = blockIdx.x * 256 + threadIdx.x;
    if (e >= NEDGE) return;
    int s = src[e], d = dst[e];
    int ps = atomicAdd(&cnt_src[s], 1);
    if (ps < CAP_L) bsrc[(size_t)s * CAP_L + ps] = d;
    int pd = atomicAdd(&cnt_dst[d], 1);
    if (pd < CAP_T) bdst[(size_t)d * CAP_T + pd] = s;
}

// ---------------------------------------------------------------------------
// K2: fused target pipeline, 512 threads (8 waves).
// ---------------------------------------------------------------------------
__global__ __launch_bounds__(512) void k_tgt1m(
    const uint4* __restrict__ xtf,    // [250*40][64] bf16 A-frags
    const uint4* __restrict__ Wf1,    // [640][64] bf16 B-frags
    const uint4* __restrict__ Wf2,    // [64][64] bf16 B-frags (conv2)
    const float* __restrict__ xl,
    const int* __restrict__ bdst, const int* __restrict__ cnt_dst,
    const float* __restrict__ W1lt_l, // [4,128]
    const float* __restrict__ b1lt,
    float* __restrict__ y_t1,
    float* __restrict__ y_t2, float* __restrict__ htW2r)
{
    __shared__ float  ms[16][4];
    __shared__ ushort hts[16][136];

    int w = threadIdx.x >> 6;         // 0..7
    int lane = threadIdx.x & 63;
    int l15 = lane & 15, g = lane >> 4;
    int rt = blockIdx.x;
    int row0 = rt * 16;

    // phase A: neighbor mean of x_l
    if (threadIdx.x < 128) {
        int r = threadIdx.x >> 3, lane8 = threadIdx.x & 7;
        int row = row0 + r;
        int deg = cnt_dst[row];
        int n = min(deg, CAP_T);
        float4 acc = make_float4(0.f, 0.f, 0.f, 0.f);
        for (int i = lane8; i < n; i += 8) {
            int sid = bdst[(size_t)row * CAP_T + i];
            float4 x = *reinterpret_cast<const float4*>(xl + 4ull * (unsigned)sid);
            acc.x += x.x; acc.y += x.y; acc.z += x.z; acc.w += x.w;
        }
#pragma unroll
        for (int off = 1; off < 8; off <<= 1) {
            acc.x += __shfl_xor(acc.x, off); acc.y += __shfl_xor(acc.y, off);
            acc.z += __shfl_xor(acc.z, off); acc.w += __shfl_xor(acc.w, off);
        }
        if (lane8 == 0) {
            float dinv = 1.0f / fmaxf((float)deg, 1.0f);
            ms[r][0] = acc.x * dinv; ms[r][1] = acc.y * dinv;
            ms[r][2] = acc.z * dinv; ms[r][3] = acc.w * dinv;
        }
    }

    // phase B: conv1 MFMA K-loop
    f32x4 acc[2];
#pragma unroll
    for (int ct = 0; ct < 2; ++ct) acc[ct] = (f32x4){0.f, 0.f, 0.f, 0.f};

    for (int ks = 0; ks < DT / 32; ++ks) {
        union { uint4 u; short8v s; } ua;
        ua.u = xtf[(size_t)(rt * 40 + ks) * 64 + lane];
#pragma unroll
        for (int ct = 0; ct < 2; ++ct) {
            union { uint4 u; short8v s; } ub;
            ub.u = Wf1[(size_t)(ks * 16 + w * 2 + ct) * 64 + lane];
            acc[ct] = __builtin_amdgcn_mfma_f32_16x16x32_bf16(ua.s, ub.s, acc[ct], 0, 0, 0);
        }
    }

    __syncthreads();

    // phase C: h_t -> LDS bf16 (waves 0-3); y_t1 -> global (waves 4-7)
    if (w < 4) {
#pragma unroll
        for (int ct = 0; ct < 2; ++ct) {
            int c = w * 32 + ct * 16 + l15;
            float wl0 = W1lt_l[c], wl1 = W1lt_l[HD + c],
                  wl2 = W1lt_l[2 * HD + c], wl3 = W1lt_l[3 * HD + c];
            float bb = b1lt[c];
#pragma unroll
            for (int j = 0; j < 4; ++j) {
                int r = 4 * g + j;
                float v = acc[ct][j] + bb + ms[r][0] * wl0 + ms[r][1] * wl1
                        + ms[r][2] * wl2 + ms[r][3] * wl3;
                hts[r][c] = f2bf(fmaxf(v, 0.0f));
            }
        }
    } else {
#pragma unroll
        for (int ct = 0; ct < 2; ++ct) {
            int c = (w - 4) * 32 + ct * 16 + l15;
#pragma unroll
            for (int j = 0; j < 4; ++j) {
                int grow = row0 + 4 * g + j;
                y_t1[(size_t)grow * HD + c] = acc[ct][j];
            }
        }
    }
    __syncthreads();

    // phase D: conv2 MFMA (K=128) from LDS h_t
    f32x4 acc2[2];
#pragma unroll
    for (int ct = 0; ct < 2; ++ct) acc2[ct] = (f32x4){0.f, 0.f, 0.f, 0.f};

#pragma unroll
    for (int ks2 = 0; ks2 < 4; ++ks2) {
        int kb2 = ks2 * 32 + g * 4;
        union { ushort us[8]; short8v s; } ua2;
        *reinterpret_cast<ushort4*>(&ua2.us[0]) =
            *reinterpret_cast<const ushort4*>(&hts[l15][kb2]);
        *reinterpret_cast<ushort4*>(&ua2.us[4]) =
            *reinterpret_cast<const ushort4*>(&hts[l15][kb2 + 16]);
#pragma unroll
        for (int ct = 0; ct < 2; ++ct) {
            union { uint4 u; short8v s; } ub2;
            ub2.u = Wf2[(size_t)(ks2 * 16 + w * 2 + ct) * 64 + lane];
            acc2[ct] = __builtin_amdgcn_mfma_f32_16x16x32_bf16(ua2.s, ub2.s, acc2[ct], 0, 0, 0);
        }
    }

    float* outp = (w < 4) ? y_t2 : htW2r;
    int cw = (w < 4) ? w : (w - 4);
#pragma unroll
    for (int ct = 0; ct < 2; ++ct) {
        int c = cw * 32 + ct * 16 + l15;
#pragma unroll
        for (int j = 0; j < 4; ++j) {
            int grow = row0 + 4 * g + j;
            outp[(size_t)grow * HD + c] = acc2[ct][j];
        }
    }
}

// ---------------------------------------------------------------------------
// K3: fused ligand conv1 (round-14 structure: 16 thr/node, ONE bsrc walk
// feeding both h_l and gl2 accumulators) -> hlb + gl2, both CHUNK-ordered
// single uint4 full-line stores. No hlbf (k_pl reads A-frags from hlb).
// Chunk tc holds cols ks*32+g*4+{0..3} (us[0..3]) and +16..+19 (us[4..7]).
// ---------------------------------------------------------------------------
__global__ __launch_bounds__(256) void k_hl(
    const float* __restrict__ xl,
    const float* __restrict__ y_t1, const float* __restrict__ y_t2,
    const int* __restrict__ bsrc, const int* __restrict__ cnt_src,
    const float* __restrict__ W1tl_r,  // [4,128]
    const float* __restrict__ b1tl,
    uint4* __restrict__ hlb,   // [N_LIG][16] chunk-ordered
    uint4* __restrict__ gl2)   // [N_LIG][16] chunk-ordered
{
    int tc = threadIdx.x & 15;
    int node = blockIdx.x * 16 + (threadIdx.x >> 4);
    int ks = tc >> 2, g = tc & 3;
    int kb = ks * 32 + g * 4;

    int deg = cnt_src[node];
    int n = min(deg, CAP_L);
    float4 s0 = make_float4(0.f, 0.f, 0.f, 0.f);
    float4 s1 = make_float4(0.f, 0.f, 0.f, 0.f);
    float4 t0 = make_float4(0.f, 0.f, 0.f, 0.f);
    float4 t1 = make_float4(0.f, 0.f, 0.f, 0.f);
    for (int i = 0; i < n; ++i) {
        int did = bsrc[(size_t)node * CAP_L + i];
        float4 v0 = *reinterpret_cast<const float4*>(y_t1 + (size_t)did * HD + kb);
        float4 v1 = *reinterpret_cast<const float4*>(y_t1 + (size_t)did * HD + kb + 16);
        float4 u0 = *reinterpret_cast<const float4*>(y_t2 + (size_t)did * HD + kb);
        float4 u1 = *reinterpret_cast<const float4*>(y_t2 + (size_t)did * HD + kb + 16);
        s0.x += v0.x; s0.y += v0.y; s0.z += v0.z; s0.w += v0.w;
        s1.x += v1.x; s1.y += v1.y; s1.z += v1.z; s1.w += v1.w;
        t0.x += u0.x; t0.y += u0.y; t0.z += u0.z; t0.w += u0.w;
        t1.x += u1.x; t1.y += u1.y; t1.z += u1.z; t1.w += u1.w;
    }
    float dinv = 1.0f / fmaxf((float)deg, 1.0f);
    float4 x = *reinterpret_cast<const float4*>(xl + 4ull * (unsigned)node);

    float4 b0 = *reinterpret_cast<const float4*>(b1tl + kb);
    float4 b1 = *reinterpret_cast<const float4*>(b1tl + kb + 16);
    float4 wa0 = *reinterpret_cast<const float4*>(W1tl_r + 0 * HD + kb);
    float4 wa1 = *reinterpret_cast<const float4*>(W1tl_r + 1 * HD + kb);
    float4 wa2 = *reinterpret_cast<const float4*>(W1tl_r + 2 * HD + kb);
    float4 wa3 = *reinterpret_cast<const float4*>(W1tl_r + 3 * HD + kb);
    float4 wb0 = *reinterpret_cast<const float4*>(W1tl_r + 0 * HD + kb + 16);
    float4 wb1 = *reinterpret_cast<const float4*>(W1tl_r + 1 * HD + kb + 16);
    float4 wb2 = *reinterpret_cast<const float4*>(W1tl_r + 2 * HD + kb + 16);
    float4 wb3 = *reinterpret_cast<const float4*>(W1tl_r + 3 * HD + kb + 16);

    union { ushort us[8]; uint4 u; } o;
    o.us[0] = f2bf(fmaxf(s0.x * dinv + b0.x + x.x * wa0.x + x.y * wa1.x + x.z * wa2.x + x.w * wa3.x, 0.f));
    o.us[1] = f2bf(fmaxf(s0.y * dinv + b0.y + x.x * wa0.y + x.y * wa1.y + x.z * wa2.y + x.w * wa3.y, 0.f));
    o.us[2] = f2bf(fmaxf(s0.z * dinv + b0.z + x.x * wa0.z + x.y * wa1.z + x.z * wa2.z + x.w * wa3.z, 0.f));
    o.us[3] = f2bf(fmaxf(s0.w * dinv + b0.w + x.x * wa0.w + x.y * wa1.w + x.z * wa2.w + x.w * wa3.w, 0.f));
    o.us[4] = f2bf(fmaxf(s1.x * dinv + b1.x + x.x * wb0.x + x.y * wb1.x + x.z * wb2.x + x.w * wb3.x, 0.f));
    o.us[5] = f2bf(fmaxf(s1.y * dinv + b1.y + x.x * wb0.y + x.y * wb1.y + x.z * wb2.y + x.w * wb3.y, 0.f));
    o.us[6] = f2bf(fmaxf(s1.z * dinv + b1.z + x.x * wb0.z + x.y * wb1.z + x.z * wb2.z + x.w * wb3.z, 0.f));
    o.us[7] = f2bf(fmaxf(s1.w * dinv + b1.w + x.x * wb0.w + x.y * wb1.w + x.z * wb2.w + x.w * wb3.w, 0.f));
    hlb[(size_t)node * 16 + tc] = o.u;

    union { ushort us[8]; uint4 u; } q;
    q.us[0] = f2bf(t0.x * dinv); q.us[1] = f2bf(t0.y * dinv);
    q.us[2] = f2bf(t0.z * dinv); q.us[3] = f2bf(t0.w * dinv);
    q.us[4] = f2bf(t1.x * dinv); q.us[5] = f2bf(t1.y * dinv);
    q.us[6] = f2bf(t1.z * dinv); q.us[7] = f2bf(t1.w * dinv);
    gl2[(size_t)node * 16 + tc] = q.u;
}

// ---------------------------------------------------------------------------
// K5+K6 merged predictors (256 threads).
//   blockIdx < N_TGT: target row — LDS-staged indices, 16x16 uint4 gather
//     from chunk-ordered hlb, un-permute in msh phase (verified round 16).
//   else: ligand MFMA, A-frags read directly from chunk-ordered hlb
//     (chunk (ks,g) == A-fragment register layout), gl2 off8 epilogue.
// ---------------------------------------------------------------------------
__global__ __launch_bounds__(256) void k_ptl(
    const uint4* __restrict__ hlb,    // chunk-ordered
    const uint4* __restrict__ Wf,
    const ushort* __restrict__ gl2,   // chunk-ordered (scalar reads)
    const int* __restrict__ bdst, const int* __restrict__ cnt_dst,
    const float* __restrict__ Wlt,    // W2lt_l [128,128]
    const float* __restrict__ b2lt,
    const float* __restrict__ b2tl,
    const float* __restrict__ htW2r,
    const float* __restrict__ Wp,     // [256]
    float* __restrict__ p_t, float* __restrict__ p_l)
{
    __shared__ int   idx[CAP_T];
    __shared__ float sm[16][132];
    __shared__ float msh[HD];
    __shared__ float sum2[2];

    if (blockIdx.x < N_TGT) {
        int row = blockIdx.x;
        int deg = cnt_dst[row];
        int nn = min(deg, CAP_T);

        if (threadIdx.x < CAP_T) idx[threadIdx.x] = bdst[(size_t)row * CAP_T + threadIdx.x];
        __syncthreads();

        // 16 groups x 16 lanes; lane loads chunk l16 (16B)
        int wg = threadIdx.x >> 4, l16 = threadIdx.x & 15;
        float s[8];
#pragma unroll
        for (int j = 0; j < 8; ++j) s[j] = 0.f;
        for (int i = wg; i < nn; i += 16) {
            int sid = idx[i];
            union { uint4 u; ushort us[8]; } v;
            v.u = hlb[(size_t)sid * 16 + l16];
#pragma unroll
            for (int j = 0; j < 8; ++j) s[j] += bf2f(v.us[j]);
        }
#pragma unroll
        for (int j = 0; j < 8; ++j) sm[wg][l16 * 8 + j] = s[j];
        __syncthreads();

        if (threadIdx.x < HD) {
            int h = threadIdx.x;
            int tc2 = h >> 3, jj = h & 7;
            float dinv = 1.0f / fmaxf((float)deg, 1.0f);
            float acc = 0.f;
#pragma unroll
            for (int w2 = 0; w2 < 16; ++w2) acc += sm[w2][tc2 * 8 + jj];
            // chunk tc2=(ks,g): us[jj] -> col = ks*32 + (jj>=4)*16 + g*4 + (jj&3)
            int ks2 = tc2 >> 2, g2 = tc2 & 3;
            int col = ks2 * 32 + ((jj >> 2) << 4) + g2 * 4 + (jj & 3);
            msh[col] = acc * dinv;
        }
        __syncthreads();

        if (threadIdx.x < HD) {
            int h = threadIdx.x;
            float g = 0.f;
            for (int k = 0; k < HD; k += 4) {
                float4 mk = *reinterpret_cast<const float4*>(&msh[k]);
                g += mk.x * Wlt[(size_t)(k + 0) * HD + h] + mk.y * Wlt[(size_t)(k + 1) * HD + h]
                   + mk.z * Wlt[(size_t)(k + 2) * HD + h] + mk.w * Wlt[(size_t)(k + 3) * HD + h];
            }
            float v = fmaxf(g + b2lt[h] + htW2r[(size_t)row * HD + h], 0.0f);
            float part = v * Wp[HD + h];
#pragma unroll
            for (int off = 1; off < 64; off <<= 1) part += __shfl_xor(part, off);
            if ((h & 63) == 0) sum2[h >> 6] = part;
        }
        __syncthreads();
        if (threadIdx.x == 0) p_t[row] = sum2[0] + sum2[1];
        return;
    }

    // ---- ligand branch: 4 tiles/block, A-frags straight from hlb ----
    int wid = threadIdx.x >> 6;
    int lane = threadIdx.x & 63;
    int l15 = lane & 15, g = lane >> 4;
    int tile = (blockIdx.x - N_TGT) * 4 + wid;
    int wrow0 = tile * 16;

    int arow = wrow0 + l15;
    if (arow >= N_LIG) arow = N_LIG - 1;

    f32x4 acc[8];
#pragma unroll
    for (int ct = 0; ct < 8; ++ct) acc[ct] = (f32x4){0.f, 0.f, 0.f, 0.f};

#pragma unroll
    for (int ks = 0; ks < 4; ++ks) {
        union { uint4 u; short8v s; } ua;
        ua.u = hlb[(size_t)arow * 16 + ks * 4 + g];
#pragma unroll
        for (int ct = 0; ct < 8; ++ct) {
            union { uint4 u; short8v s; } ub;
            ub.u = Wf[(ks * 8 + ct) * 64 + lane];
            acc[ct] = __builtin_amdgcn_mfma_f32_16x16x32_bf16(ua.s, ub.s, acc[ct], 0, 0, 0);
        }
    }

    float wpv[8], bv[8];
    int off8[8];
#pragma unroll
    for (int ct = 0; ct < 8; ++ct) {
        int c = ct * 16 + l15;
        wpv[ct] = Wp[c];
        bv[ct]  = b2tl[c];
        // col c -> chunk-ordered pos: chunk=(c>>5)*4+((c&15)>>2), elem=((c>>4)&1)*4+(c&3)
        off8[ct] = (((ct >> 1) * 4 + (l15 >> 2)) << 3) + ((ct & 1) << 2) + (l15 & 3);
    }

#pragma unroll
    for (int j = 0; j < 4; ++j) {
        int row = wrow0 + g * 4 + j;
        bool valid = row < N_LIG;
        int lrow = valid ? row : 0;
        const ushort* gp = gl2 + (size_t)lrow * HD;
        float part = 0.f;
#pragma unroll
        for (int ct = 0; ct < 8; ++ct) {
            float v = acc[ct][j] + bf2f(gp[off8[ct]]) + bv[ct];
            part += fmaxf(v, 0.f) * wpv[ct];
        }
#pragma unroll
        for (int off = 1; off < 16; off <<= 1) part += __shfl_xor(part, off);
        if (valid && l15 == 0) p_l[row] = part;
    }
}

// ---------------------------------------------------------------------------
// K7: out[e] = p_l[src[e]] + p_t[dst[e]] + bp
// ---------------------------------------------------------------------------
__global__ __launch_bounds__(256) void k_out(
    const int* __restrict__ src, const int* __restrict__ dst,
    const float* __restrict__ p_l, const float* __restrict__ p_t,
    const float* __restrict__ bp, float* __restrict__ out)
{
    int e = blockIdx.x * 256 + threadIdx.x;
    if (e >= NEDGE) return;
    out[e] = p_l[src[e]] + p_t[dst[e]] + bp[0];
}

// ---------------------------------------------------------------------------
extern "C" void kernel_launch(void* const* d_in, const int* in_sizes, int n_in,
                              void* d_out, int out_size, void* d_ws, size_t ws_size,
                              hipStream_t stream)
{
    const float* x_l    = (const float*)d_in[0];
    const float* x_t    = (const float*)d_in[1];
    const int*   ei     = (const int*)  d_in[2];
    const float* W1lt_l = (const float*)d_in[3];
    const float* b1lt   = (const float*)d_in[4];
    const float* W1lt_r = (const float*)d_in[5];
    const float* W1tl_l = (const float*)d_in[6];
    const float* b1tl   = (const float*)d_in[7];
    const float* W1tl_r = (const float*)d_in[8];
    const float* W2lt_l = (const float*)d_in[9];
    const float* b2lt   = (const float*)d_in[10];
    const float* W2lt_r = (const float*)d_in[11];
    const float* W2tl_l = (const float*)d_in[12];
    const float* b2tl   = (const float*)d_in[13];
    const float* W2tl_r = (const float*)d_in[14];
    const float* Wp     = (const float*)d_in[15];
    const float* bp     = (const float*)d_in[16];

    const int* src = ei;            // ligand indices
    const int* dst = ei + NEDGE;    // target indices

    char* ws = (char*)d_ws;
    size_t o = 0;
    int* cnt_src = (int*)(ws + o); o += (size_t)N_LIG * 4;
    int* cnt_dst = (int*)(ws + o); o += (size_t)N_TGT * 4;
    int* bsrc = (int*)(ws + o); o += (size_t)N_LIG * CAP_L * 4;
    int* bdst = (int*)(ws + o); o += (size_t)N_TGT * CAP_T * 4;
    uint4* hlb   = (uint4*)(ws + o);  o += (size_t)N_LIG * HD * 2;
    uint4* gl2   = (uint4*)(ws + o);  o += (size_t)N_LIG * HD * 2;
    uint4* Wf    = (uint4*)(ws + o);  o += (size_t)32 * 64 * 16;
    uint4* Wf1   = (uint4*)(ws + o);  o += (size_t)640 * 64 * 16;
    uint4* Wf2   = (uint4*)(ws + o);  o += (size_t)64 * 64 * 16;
    uint4* xtf   = (uint4*)(ws + o);  o += (size_t)10000 * 64 * 16;
    float* y_t1  = (float*)(ws + o); o += (size_t)N_TGT * HD * 4;
    float* y_t2  = (float*)(ws + o); o += (size_t)N_TGT * HD * 4;
    float* htW2r = (float*)(ws + o); o += (size_t)N_TGT * HD * 4;
    float* p_l   = (float*)(ws + o); o += (size_t)N_LIG * 4;
    float* p_t   = (float*)(ws + o); o += (size_t)N_TGT * 4;

    float* out = (float*)d_out;

    // merged prep: fragment packing (incl. conv2 weights) + counter zeroing
    k_pack<<<2786, 256, 0, stream>>>(W2tl_r, Wf, W1lt_r, W1tl_l, Wf1,
                                     x_t, xtf, (int4*)cnt_src,
                                     W2tl_l, W2lt_r, Wf2);

    k_fill<<<(NEDGE + 255) / 256, 256, 0, stream>>>(src, dst, cnt_src, cnt_dst, bsrc, bdst);

    // fused target pipeline: conv1 + neighbor-mean + conv2 projections
    k_tgt1m<<<N_TGT / 16, 512, 0, stream>>>(xtf, Wf1, Wf2, x_l, bdst, cnt_dst,
                                            W1lt_l, b1lt, y_t1, y_t2, htW2r);

    // ligand conv1: 16 thr/node, one bsrc walk, chunk-ordered full-line stores
    k_hl<<<NTILE_L, 256, 0, stream>>>(x_l, y_t1, y_t2, bsrc, cnt_src,
                                      W1tl_r, b1tl, hlb, gl2);

    // merged predictors (target gather-GEMM + ligand MFMA streaming)
    k_ptl<<<N_TGT + PL_BLOCKS, 256, 0, stream>>>(hlb, Wf, (const ushort*)gl2,
                                                 bdst, cnt_dst,
                                                 W2lt_l, b2lt, b2tl, htW2r, Wp,
                                                 p_t, p_l);

    // edges
    k_out<<<(NEDGE + 255) / 256, 256, 0, stream>>>(src, dst, p_l, p_t, bp, out);
}

// Round 19
// 103.515 us; speedup vs baseline: 1.2700x; 1.0392x over previous
//
#include <hip/hip_runtime.h>
#include <hip/hip_bf16.h>

#define N_LIG 100000
#define N_TGT 4000
#define NEDGE 150000
#define DT 1280
#define HD 128
#define CAP_L 32
#define CAP_T 128
#define NTILE_L 6250            // N_LIG / 16

typedef __attribute__((ext_vector_type(8))) short short8v;
typedef __attribute__((ext_vector_type(4))) float f32x4;

static __device__ __forceinline__ ushort f2bf(float f) {
    __hip_bfloat16 h = __float2bfloat16(f);
    union { __hip_bfloat16 h; ushort u; } c; c.h = h; return c.u;
}
static __device__ __forceinline__ float bf2f(ushort u) {
    union { unsigned v; float f; } c; c.v = ((unsigned)u) << 16; return c.f;
}

// ---------------------------------------------------------------------------
// K0: merged prep — fragment packing for all MFMA operands + counter zeroing.
// ---------------------------------------------------------------------------
__global__ __launch_bounds__(256) void k_pack(
    const float* __restrict__ W2, uint4* __restrict__ Wf,
    const float* __restrict__ Wr, const float* __restrict__ Wl,
    uint4* __restrict__ Wf1,
    const float* __restrict__ xt, uint4* __restrict__ xtf,
    int4* __restrict__ cntz,
    const float* __restrict__ W2a, const float* __restrict__ W2b,
    uint4* __restrict__ Wf2)
{
    int bx = blockIdx.x;
    if (bx < 8) {
        int gid = bx * 256 + threadIdx.x;           // 2048
        int lane = gid & 63, frag = gid >> 6;       // frag 0..31
        int ks = frag >> 3, ct = frag & 7;
        int l15 = lane & 15, g = lane >> 4;
        int k = ks * 32 + g * 4, n = ct * 16 + l15;
        union { ushort us[8]; uint4 u; } o;
#pragma unroll
        for (int j = 0; j < 4; ++j) {
            o.us[j]     = f2bf(W2[(size_t)(k + j) * HD + n]);
            o.us[4 + j] = f2bf(W2[(size_t)(k + 16 + j) * HD + n]);
        }
        Wf[gid] = o.u;
    } else if (bx < 168) {
        int gid = (bx - 8) * 256 + threadIdx.x;     // 40960
        int lane = gid & 63, frag = gid >> 6;       // 0..639
        int ks = frag >> 4, nct = frag & 15;
        int l15 = lane & 15, g = lane >> 4;
        int k = ks * 32 + g * 4, n = nct * 16 + l15;
        const float* Ws = (n < HD) ? Wr : Wl;
        int nn = n & 127;
        union { ushort us[8]; uint4 u; } o;
#pragma unroll
        for (int j = 0; j < 4; ++j) {
            o.us[j]     = f2bf(Ws[(size_t)(k + j) * HD + nn]);
            o.us[4 + j] = f2bf(Ws[(size_t)(k + 16 + j) * HD + nn]);
        }
        Wf1[gid] = o.u;
    } else if (bx < 2668) {
        int gid = (bx - 168) * 256 + threadIdx.x;   // 640000
        int lane = gid & 63, frag = gid >> 6;       // 0..9999
        int ks = frag % 40, rt = frag / 40;
        int row = rt * 16 + (lane & 15);
        int kb = ks * 32 + (lane >> 4) * 4;
        float4 a0 = *reinterpret_cast<const float4*>(xt + (size_t)row * DT + kb);
        float4 a1 = *reinterpret_cast<const float4*>(xt + (size_t)row * DT + kb + 16);
        union { ushort us[8]; uint4 u; } o;
        o.us[0] = f2bf(a0.x); o.us[1] = f2bf(a0.y); o.us[2] = f2bf(a0.z); o.us[3] = f2bf(a0.w);
        o.us[4] = f2bf(a1.x); o.us[5] = f2bf(a1.y); o.us[6] = f2bf(a1.z); o.us[7] = f2bf(a1.w);
        xtf[gid] = o.u;
    } else if (bx < 2770) {
        int i = (bx - 2668) * 256 + threadIdx.x;
        if (i < 26000) cntz[i] = make_int4(0, 0, 0, 0);
    } else {
        int gid = (bx - 2770) * 256 + threadIdx.x;  // 4096
        int lane = gid & 63, frag = gid >> 6;       // 0..63
        int ks = frag >> 4, nct = frag & 15;
        int l15 = lane & 15, g = lane >> 4;
        int k = ks * 32 + g * 4, n = nct * 16 + l15;
        const float* Ws = (n < HD) ? W2a : W2b;
        int nn = n & 127;
        union { ushort us[8]; uint4 u; } o;
#pragma unroll
        for (int j = 0; j < 4; ++j) {
            o.us[j]     = f2bf(Ws[(size_t)(k + j) * HD + nn]);
            o.us[4 + j] = f2bf(Ws[(size_t)(k + 16 + j) * HD + nn]);
        }
        Wf2[gid] = o.u;
    }
}

// ---------------------------------------------------------------------------
// K1: build adjacency buckets (int atomics only).
// ---------------------------------------------------------------------------
__global__ __launch_bounds__(256) void k_fill(
    const int* __restrict__ src, const int* __restrict__ dst,
    int* __restrict__ cnt_src, int* __restrict__ cnt_dst,
    int* __restrict__ bsrc, int* __restrict__ bdst)
{
    int e = blockIdx.x * 256 + threadIdx.x;
    if (e >= NEDGE) return;
    int s = src[e], d = dst[e];
    int ps = atomicAdd(&cnt_src[s], 1);
    if (ps < CAP_L) bsrc[(size_t)s * CAP_L + ps] = d;
    int pd = atomicAdd(&cnt_dst[d], 1);
    if (pd < CAP_T) bdst[(size_t)d * CAP_T + pd] = s;
}

// ---------------------------------------------------------------------------
// K2: fused target pipeline, 512 threads (8 waves).
// ---------------------------------------------------------------------------
__global__ __launch_bounds__(512) void k_tgt1m(
    const uint4* __restrict__ xtf,    // [250*40][64] bf16 A-frags
    const uint4* __restrict__ Wf1,    // [640][64] bf16 B-frags
    const uint4* __restrict__ Wf2,    // [64][64] bf16 B-frags (conv2)
    const float* __restrict__ xl,
    const int* __restrict__ bdst, const int* __restrict__ cnt_dst,
    const float* __restrict__ W1lt_l, // [4,128]
    const float* __restrict__ b1lt,
    float* __restrict__ y_t1,
    float* __restrict__ y_t2, float* __restrict__ htW2r)
{
    __shared__ float  ms[16][4];
    __shared__ ushort hts[16][136];

    int w = threadIdx.x >> 6;         // 0..7
    int lane = threadIdx.x & 63;
    int l15 = lane & 15, g = lane >> 4;
    int rt = blockIdx.x;
    int row0 = rt * 16;

    // phase A: neighbor mean of x_l
    if (threadIdx.x < 128) {
        int r = threadIdx.x >> 3, lane8 = threadIdx.x & 7;
        int row = row0 + r;
        int deg = cnt_dst[row];
        int n = min(deg, CAP_T);
        float4 acc = make_float4(0.f, 0.f, 0.f, 0.f);
        for (int i = lane8; i < n; i += 8) {
            int sid = bdst[(size_t)row * CAP_T + i];
            float4 x = *reinterpret_cast<const float4*>(xl + 4ull * (unsigned)sid);
            acc.x += x.x; acc.y += x.y; acc.z += x.z; acc.w += x.w;
        }
#pragma unroll
        for (int off = 1; off < 8; off <<= 1) {
            acc.x += __shfl_xor(acc.x, off); acc.y += __shfl_xor(acc.y, off);
            acc.z += __shfl_xor(acc.z, off); acc.w += __shfl_xor(acc.w, off);
        }
        if (lane8 == 0) {
            float dinv = 1.0f / fmaxf((float)deg, 1.0f);
            ms[r][0] = acc.x * dinv; ms[r][1] = acc.y * dinv;
            ms[r][2] = acc.z * dinv; ms[r][3] = acc.w * dinv;
        }
    }

    // phase B: conv1 MFMA K-loop
    f32x4 acc[2];
#pragma unroll
    for (int ct = 0; ct < 2; ++ct) acc[ct] = (f32x4){0.f, 0.f, 0.f, 0.f};

    for (int ks = 0; ks < DT / 32; ++ks) {
        union { uint4 u; short8v s; } ua;
        ua.u = xtf[(size_t)(rt * 40 + ks) * 64 + lane];
#pragma unroll
        for (int ct = 0; ct < 2; ++ct) {
            union { uint4 u; short8v s; } ub;
            ub.u = Wf1[(size_t)(ks * 16 + w * 2 + ct) * 64 + lane];
            acc[ct] = __builtin_amdgcn_mfma_f32_16x16x32_bf16(ua.s, ub.s, acc[ct], 0, 0, 0);
        }
    }

    __syncthreads();

    // phase C: h_t -> LDS bf16 (waves 0-3); y_t1 -> global (waves 4-7)
    if (w < 4) {
#pragma unroll
        for (int ct = 0; ct < 2; ++ct) {
            int c = w * 32 + ct * 16 + l15;
            float wl0 = W1lt_l[c], wl1 = W1lt_l[HD + c],
                  wl2 = W1lt_l[2 * HD + c], wl3 = W1lt_l[3 * HD + c];
            float bb = b1lt[c];
#pragma unroll
            for (int j = 0; j < 4; ++j) {
                int r = 4 * g + j;
                float v = acc[ct][j] + bb + ms[r][0] * wl0 + ms[r][1] * wl1
                        + ms[r][2] * wl2 + ms[r][3] * wl3;
                hts[r][c] = f2bf(fmaxf(v, 0.0f));
            }
        }
    } else {
#pragma unroll
        for (int ct = 0; ct < 2; ++ct) {
            int c = (w - 4) * 32 + ct * 16 + l15;
#pragma unroll
            for (int j = 0; j < 4; ++j) {
                int grow = row0 + 4 * g + j;
                y_t1[(size_t)grow * HD + c] = acc[ct][j];
            }
        }
    }
    __syncthreads();

    // phase D: conv2 MFMA (K=128) from LDS h_t
    f32x4 acc2[2];
#pragma unroll
    for (int ct = 0; ct < 2; ++ct) acc2[ct] = (f32x4){0.f, 0.f, 0.f, 0.f};

#pragma unroll
    for (int ks2 = 0; ks2 < 4; ++ks2) {
        int kb2 = ks2 * 32 + g * 4;
        union { ushort us[8]; short8v s; } ua2;
        *reinterpret_cast<ushort4*>(&ua2.us[0]) =
            *reinterpret_cast<const ushort4*>(&hts[l15][kb2]);
        *reinterpret_cast<ushort4*>(&ua2.us[4]) =
            *reinterpret_cast<const ushort4*>(&hts[l15][kb2 + 16]);
#pragma unroll
        for (int ct = 0; ct < 2; ++ct) {
            union { uint4 u; short8v s; } ub2;
            ub2.u = Wf2[(size_t)(ks2 * 16 + w * 2 + ct) * 64 + lane];
            acc2[ct] = __builtin_amdgcn_mfma_f32_16x16x32_bf16(ua2.s, ub2.s, acc2[ct], 0, 0, 0);
        }
    }

    float* outp = (w < 4) ? y_t2 : htW2r;
    int cw = (w < 4) ? w : (w - 4);
#pragma unroll
    for (int ct = 0; ct < 2; ++ct) {
        int c = cw * 32 + ct * 16 + l15;
#pragma unroll
        for (int j = 0; j < 4; ++j) {
            int grow = row0 + 4 * g + j;
            outp[(size_t)grow * HD + c] = acc2[ct][j];
        }
    }
}

// ---------------------------------------------------------------------------
// K3: FUSED ligand pipeline (conv1 gather + conv2 MFMA + predictor).
// Phase 1 (16 thr/node, one bsrc walk): h_l chunk -> hlb (global, for k_pt)
//   and LDS Ah; gl2 chunk -> LDS Gh only (no global round-trip).
// Phase 2 (4 waves x 2 col-tiles): MFMA A from LDS Ah (chunk==A-frag),
//   B from Wf; epilogue adds Gh scalar (off8 map) + bias, relu, dot wp_l;
//   16-lane reduce -> per-wave partials -> final 16-thread sum -> p_l.
// ---------------------------------------------------------------------------
__global__ __launch_bounds__(256) void k_hlp(
    const float* __restrict__ xl,
    const float* __restrict__ y_t1, const float* __restrict__ y_t2,
    const int* __restrict__ bsrc, const int* __restrict__ cnt_src,
    const float* __restrict__ W1tl_r,  // [4,128]
    const float* __restrict__ b1tl,
    const uint4* __restrict__ Wf,      // [32][64] conv2 B-frags
    const float* __restrict__ b2tl,
    const float* __restrict__ Wp,      // [256]; ligand part = Wp[0..127]
    uint4* __restrict__ hlb,           // [N_LIG][16] chunk-ordered
    float* __restrict__ p_l)
{
    __shared__ uint4 Ah[16][17];       // padded: row stride 272B
    __shared__ uint4 Gh[16][17];
    __shared__ float plp[4][16];

    int tc = threadIdx.x & 15;
    int nd = threadIdx.x >> 4;         // local node 0..15
    int node = blockIdx.x * 16 + nd;
    int ks = tc >> 2, g = tc & 3;
    int kb = ks * 32 + g * 4;

    // ---- phase 1: gather + conv1 epilogue ----
    {
        int deg = cnt_src[node];
        int n = min(deg, CAP_L);
        float4 s0 = make_float4(0.f, 0.f, 0.f, 0.f);
        float4 s1 = make_float4(0.f, 0.f, 0.f, 0.f);
        float4 t0 = make_float4(0.f, 0.f, 0.f, 0.f);
        float4 t1 = make_float4(0.f, 0.f, 0.f, 0.f);
        for (int i = 0; i < n; ++i) {
            int did = bsrc[(size_t)node * CAP_L + i];
            float4 v0 = *reinterpret_cast<const float4*>(y_t1 + (size_t)did * HD + kb);
            float4 v1 = *reinterpret_cast<const float4*>(y_t1 + (size_t)did * HD + kb + 16);
            float4 u0 = *reinterpret_cast<const float4*>(y_t2 + (size_t)did * HD + kb);
            float4 u1 = *reinterpret_cast<const float4*>(y_t2 + (size_t)did * HD + kb + 16);
            s0.x += v0.x; s0.y += v0.y; s0.z += v0.z; s0.w += v0.w;
            s1.x += v1.x; s1.y += v1.y; s1.z += v1.z; s1.w += v1.w;
            t0.x += u0.x; t0.y += u0.y; t0.z += u0.z; t0.w += u0.w;
            t1.x += u1.x; t1.y += u1.y; t1.z += u1.z; t1.w += u1.w;
        }
        float dinv = 1.0f / fmaxf((float)deg, 1.0f);
        float4 x = *reinterpret_cast<const float4*>(xl + 4ull * (unsigned)node);

        float4 b0 = *reinterpret_cast<const float4*>(b1tl + kb);
        float4 b1 = *reinterpret_cast<const float4*>(b1tl + kb + 16);
        float4 wa0 = *reinterpret_cast<const float4*>(W1tl_r + 0 * HD + kb);
        float4 wa1 = *reinterpret_cast<const float4*>(W1tl_r + 1 * HD + kb);
        float4 wa2 = *reinterpret_cast<const float4*>(W1tl_r + 2 * HD + kb);
        float4 wa3 = *reinterpret_cast<const float4*>(W1tl_r + 3 * HD + kb);
        float4 wb0 = *reinterpret_cast<const float4*>(W1tl_r + 0 * HD + kb + 16);
        float4 wb1 = *reinterpret_cast<const float4*>(W1tl_r + 1 * HD + kb + 16);
        float4 wb2 = *reinterpret_cast<const float4*>(W1tl_r + 2 * HD + kb + 16);
        float4 wb3 = *reinterpret_cast<const float4*>(W1tl_r + 3 * HD + kb + 16);

        union { ushort us[8]; uint4 u; } o;
        o.us[0] = f2bf(fmaxf(s0.x * dinv + b0.x + x.x * wa0.x + x.y * wa1.x + x.z * wa2.x + x.w * wa3.x, 0.f));
        o.us[1] = f2bf(fmaxf(s0.y * dinv + b0.y + x.x * wa0.y + x.y * wa1.y + x.z * wa2.y + x.w * wa3.y, 0.f));
        o.us[2] = f2bf(fmaxf(s0.z * dinv + b0.z + x.x * wa0.z + x.y * wa1.z + x.z * wa2.z + x.w * wa3.z, 0.f));
        o.us[3] = f2bf(fmaxf(s0.w * dinv + b0.w + x.x * wa0.w + x.y * wa1.w + x.z * wa2.w + x.w * wa3.w, 0.f));
        o.us[4] = f2bf(fmaxf(s1.x * dinv + b1.x + x.x * wb0.x + x.y * wb1.x + x.z * wb2.x + x.w * wb3.x, 0.f));
        o.us[5] = f2bf(fmaxf(s1.y * dinv + b1.y + x.x * wb0.y + x.y * wb1.y + x.z * wb2.y + x.w * wb3.y, 0.f));
        o.us[6] = f2bf(fmaxf(s1.z * dinv + b1.z + x.x * wb0.z + x.y * wb1.z + x.z * wb2.z + x.w * wb3.z, 0.f));
        o.us[7] = f2bf(fmaxf(s1.w * dinv + b1.w + x.x * wb0.w + x.y * wb1.w + x.z * wb2.w + x.w * wb3.w, 0.f));
        hlb[(size_t)node * 16 + tc] = o.u;
        Ah[nd][tc] = o.u;

        union { ushort us[8]; uint4 u; } q;
        q.us[0] = f2bf(t0.x * dinv); q.us[1] = f2bf(t0.y * dinv);
        q.us[2] = f2bf(t0.z * dinv); q.us[3] = f2bf(t0.w * dinv);
        q.us[4] = f2bf(t1.x * dinv); q.us[5] = f2bf(t1.y * dinv);
        q.us[6] = f2bf(t1.z * dinv); q.us[7] = f2bf(t1.w * dinv);
        Gh[nd][tc] = q.u;
    }
    __syncthreads();

    // ---- phase 2: MFMA + predictor ----
    int w = threadIdx.x >> 6;          // wave 0..3, owns ct = 2w, 2w+1
    int lane = threadIdx.x & 63;
    int l15 = lane & 15, gq = lane >> 4;

    f32x4 acc[2];
#pragma unroll
    for (int c2 = 0; c2 < 2; ++c2) acc[c2] = (f32x4){0.f, 0.f, 0.f, 0.f};

#pragma unroll
    for (int ksq = 0; ksq < 4; ++ksq) {
        union { uint4 u; short8v s; } ua;
        ua.u = Ah[l15][ksq * 4 + gq];
#pragma unroll
        for (int c2 = 0; c2 < 2; ++c2) {
            int ct = w * 2 + c2;
            union { uint4 u; short8v s; } ub;
            ub.u = Wf[(ksq * 8 + ct) * 64 + lane];
            acc[c2] = __builtin_amdgcn_mfma_f32_16x16x32_bf16(ua.s, ub.s, acc[c2], 0, 0, 0);
        }
    }

    float wpv[2], bv[2];
    int off8[2];
#pragma unroll
    for (int c2 = 0; c2 < 2; ++c2) {
        int ct = w * 2 + c2;
        int c = ct * 16 + l15;
        wpv[c2] = Wp[c];
        bv[c2]  = b2tl[c];
        off8[c2] = (((ct >> 1) * 4 + (l15 >> 2)) << 3) + ((ct & 1) << 2) + (l15 & 3);
    }

#pragma unroll
    for (int j = 0; j < 4; ++j) {
        int r = gq * 4 + j;
        const ushort* gp = reinterpret_cast<const ushort*>(&Gh[r][0]);
        float part = 0.f;
#pragma unroll
        for (int c2 = 0; c2 < 2; ++c2) {
            // Gh row is padded [17] uint4 = 136 ushorts; off8 < 128 so direct
            float v = acc[c2][j] + bf2f(gp[off8[c2]]) + bv[c2];
            part += fmaxf(v, 0.f) * wpv[c2];
        }
#pragma unroll
        for (int off = 1; off < 16; off <<= 1) part += __shfl_xor(part, off);
        if (l15 == 0) plp[w][r] = part;
    }
    __syncthreads();

    if (threadIdx.x < 16) {
        int r = threadIdx.x;
        p_l[blockIdx.x * 16 + r] = plp[0][r] + plp[1][r] + plp[2][r] + plp[3][r];
    }
}

// ---------------------------------------------------------------------------
// K5: target predictor (LDS-staged indices, 16x16 uint4 gather from
// chunk-ordered hlb, un-permute in msh phase — verified).
// ---------------------------------------------------------------------------
__global__ __launch_bounds__(256) void k_pt(
    const uint4* __restrict__ hlb,    // chunk-ordered
    const int* __restrict__ bdst, const int* __restrict__ cnt_dst,
    const float* __restrict__ Wlt,    // W2lt_l [128,128]
    const float* __restrict__ b2lt,
    const float* __restrict__ htW2r,
    const float* __restrict__ Wp,     // [256]
    float* __restrict__ p_t)
{
    __shared__ int   idx[CAP_T];
    __shared__ float sm[16][132];
    __shared__ float msh[HD];
    __shared__ float sum2[2];

    int row = blockIdx.x;
    int deg = cnt_dst[row];
    int nn = min(deg, CAP_T);

    if (threadIdx.x < CAP_T) idx[threadIdx.x] = bdst[(size_t)row * CAP_T + threadIdx.x];
    __syncthreads();

    int wg = threadIdx.x >> 4, l16 = threadIdx.x & 15;
    float s[8];
#pragma unroll
    for (int j = 0; j < 8; ++j) s[j] = 0.f;
    for (int i = wg; i < nn; i += 16) {
        int sid = idx[i];
        union { uint4 u; ushort us[8]; } v;
        v.u = hlb[(size_t)sid * 16 + l16];
#pragma unroll
        for (int j = 0; j < 8; ++j) s[j] += bf2f(v.us[j]);
    }
#pragma unroll
    for (int j = 0; j < 8; ++j) sm[wg][l16 * 8 + j] = s[j];
    __syncthreads();

    if (threadIdx.x < HD) {
        int h = threadIdx.x;
        int tc2 = h >> 3, jj = h & 7;
        float dinv = 1.0f / fmaxf((float)deg, 1.0f);
        float acc = 0.f;
#pragma unroll
        for (int w2 = 0; w2 < 16; ++w2) acc += sm[w2][tc2 * 8 + jj];
        int ks2 = tc2 >> 2, g2 = tc2 & 3;
        int col = ks2 * 32 + ((jj >> 2) << 4) + g2 * 4 + (jj & 3);
        msh[col] = acc * dinv;
    }
    __syncthreads();

    if (threadIdx.x < HD) {
        int h = threadIdx.x;
        float g = 0.f;
        for (int k = 0; k < HD; k += 4) {
            float4 mk = *reinterpret_cast<const float4*>(&msh[k]);
            g += mk.x * Wlt[(size_t)(k + 0) * HD + h] + mk.y * Wlt[(size_t)(k + 1) * HD + h]
               + mk.z * Wlt[(size_t)(k + 2) * HD + h] + mk.w * Wlt[(size_t)(k + 3) * HD + h];
        }
        float v = fmaxf(g + b2lt[h] + htW2r[(size_t)row * HD + h], 0.0f);
        float part = v * Wp[HD + h];
#pragma unroll
        for (int off = 1; off < 64; off <<= 1) part += __shfl_xor(part, off);
        if ((h & 63) == 0) sum2[h >> 6] = part;
    }
    __syncthreads();
    if (threadIdx.x == 0) p_t[row] = sum2[0] + sum2[1];
}

// ---------------------------------------------------------------------------
// K7: out[e] = p_l[src[e]] + p_t[dst[e]] + bp
// ---------------------------------------------------------------------------
__global__ __launch_bounds__(256) void k_out(
    const int* __restrict__ src, const int* __restrict__ dst,
    const float* __restrict__ p_l, const float* __restrict__ p_t,
    const float* __restrict__ bp, float* __restrict__ out)
{
    int e = blockIdx.x * 256 + threadIdx.x;
    if (e >= NEDGE) return;
    out[e] = p_l[src[e]] + p_t[dst[e]] + bp[0];
}

// ---------------------------------------------------------------------------
extern "C" void kernel_launch(void* const* d_in, const int* in_sizes, int n_in,
                              void* d_out, int out_size, void* d_ws, size_t ws_size,
                              hipStream_t stream)
{
    const float* x_l    = (const float*)d_in[0];
    const float* x_t    = (const float*)d_in[1];
    const int*   ei     = (const int*)  d_in[2];
    const float* W1lt_l = (const float*)d_in[3];
    const float* b1lt   = (const float*)d_in[4];
    const float* W1lt_r = (const float*)d_in[5];
    const float* W1tl_l = (const float*)d_in[6];
    const float* b1tl   = (const float*)d_in[7];
    const float* W1tl_r = (const float*)d_in[8];
    const float* W2lt_l = (const float*)d_in[9];
    const float* b2lt   = (const float*)d_in[10];
    const float* W2lt_r = (const float*)d_in[11];
    const float* W2tl_l = (const float*)d_in[12];
    const float* b2tl   = (const float*)d_in[13];
    const float* W2tl_r = (const float*)d_in[14];
    const float* Wp     = (const float*)d_in[15];
    const float* bp     = (const float*)d_in[16];

    const int* src = ei;            // ligand indices
    const int* dst = ei + NEDGE;    // target indices

    char* ws = (char*)d_ws;
    size_t o = 0;
    int* cnt_src = (int*)(ws + o); o += (size_t)N_LIG * 4;
    int* cnt_dst = (int*)(ws + o); o += (size_t)N_TGT * 4;
    int* bsrc = (int*)(ws + o); o += (size_t)N_LIG * CAP_L * 4;
    int* bdst = (int*)(ws + o); o += (size_t)N_TGT * CAP_T * 4;
    uint4* hlb   = (uint4*)(ws + o);  o += (size_t)N_LIG * HD * 2;
    uint4* Wf    = (uint4*)(ws + o);  o += (size_t)32 * 64 * 16;
    uint4* Wf1   = (uint4*)(ws + o);  o += (size_t)640 * 64 * 16;
    uint4* Wf2   = (uint4*)(ws + o);  o += (size_t)64 * 64 * 16;
    uint4* xtf   = (uint4*)(ws + o);  o += (size_t)10000 * 64 * 16;
    float* y_t1  = (float*)(ws + o); o += (size_t)N_TGT * HD * 4;
    float* y_t2  = (float*)(ws + o); o += (size_t)N_TGT * HD * 4;
    float* htW2r = (float*)(ws + o); o += (size_t)N_TGT * HD * 4;
    float* p_l   = (float*)(ws + o); o += (size_t)N_LIG * 4;
    float* p_t   = (float*)(ws + o); o += (size_t)N_TGT * 4;

    float* out = (float*)d_out;

    // merged prep: fragment packing (incl. conv2 weights) + counter zeroing
    k_pack<<<2786, 256, 0, stream>>>(W2tl_r, Wf, W1lt_r, W1tl_l, Wf1,
                                     x_t, xtf, (int4*)cnt_src,
                                     W2tl_l, W2lt_r, Wf2);

    k_fill<<<(NEDGE + 255) / 256, 256, 0, stream>>>(src, dst, cnt_src, cnt_dst, bsrc, bdst);

    // fused target pipeline: conv1 + neighbor-mean + conv2 projections
    k_tgt1m<<<N_TGT / 16, 512, 0, stream>>>(xtf, Wf1, Wf2, x_l, bdst, cnt_dst,
                                            W1lt_l, b1lt, y_t1, y_t2, htW2r);

    // fused ligand pipeline: conv1 gather + conv2 MFMA + predictor
    k_hlp<<<NTILE_L, 256, 0, stream>>>(x_l, y_t1, y_t2, bsrc, cnt_src,
                                       W1tl_r, b1tl, Wf, b2tl, Wp, hlb, p_l);

    // target predictor
    k_pt<<<N_TGT, 256, 0, stream>>>(hlb, bdst, cnt_dst,
                                    W2lt_l, b2lt, htW2r, Wp, p_t);

    // edges
    k_out<<<(NEDGE + 255) / 256, 256, 0, stream>>>(src, dst, p_l, p_t, bp, out);
}

// Round 20
// 95.868 us; speedup vs baseline: 1.3713x; 1.0798x over previous
//
#include <hip/hip_runtime.h>
#include <hip/hip_bf16.h>

#define N_LIG 100000
#define N_TGT 4000
#define NEDGE 150000
#define DT 1280
#define HD 128
#define CAP_L 32
#define CAP_T 128
#define NTILE_L 6250            // N_LIG / 16

typedef __attribute__((ext_vector_type(8))) short short8v;
typedef __attribute__((ext_vector_type(4))) float f32x4;

static __device__ __forceinline__ ushort f2bf(float f) {
    __hip_bfloat16 h = __float2bfloat16(f);
    union { __hip_bfloat16 h; ushort u; } c; c.h = h; return c.u;
}
static __device__ __forceinline__ float bf2f(ushort u) {
    union { unsigned v; float f; } c; c.v = ((unsigned)u) << 16; return c.f;
}

// ---------------------------------------------------------------------------
// K0: merged prep — fragment packing for all MFMA operands + counter zeroing.
// ---------------------------------------------------------------------------
__global__ __launch_bounds__(256) void k_pack(
    const float* __restrict__ W2, uint4* __restrict__ Wf,
    const float* __restrict__ Wr, const float* __restrict__ Wl,
    uint4* __restrict__ Wf1,
    const float* __restrict__ xt, uint4* __restrict__ xtf,
    int4* __restrict__ cntz,
    const float* __restrict__ W2a, const float* __restrict__ W2b,
    uint4* __restrict__ Wf2)
{
    int bx = blockIdx.x;
    if (bx < 8) {
        int gid = bx * 256 + threadIdx.x;           // 2048
        int lane = gid & 63, frag = gid >> 6;       // frag 0..31
        int ks = frag >> 3, ct = frag & 7;
        int l15 = lane & 15, g = lane >> 4;
        int k = ks * 32 + g * 4, n = ct * 16 + l15;
        union { ushort us[8]; uint4 u; } o;
#pragma unroll
        for (int j = 0; j < 4; ++j) {
            o.us[j]     = f2bf(W2[(size_t)(k + j) * HD + n]);
            o.us[4 + j] = f2bf(W2[(size_t)(k + 16 + j) * HD + n]);
        }
        Wf[gid] = o.u;
    } else if (bx < 168) {
        int gid = (bx - 8) * 256 + threadIdx.x;     // 40960
        int lane = gid & 63, frag = gid >> 6;       // 0..639
        int ks = frag >> 4, nct = frag & 15;
        int l15 = lane & 15, g = lane >> 4;
        int k = ks * 32 + g * 4, n = nct * 16 + l15;
        const float* Ws = (n < HD) ? Wr : Wl;
        int nn = n & 127;
        union { ushort us[8]; uint4 u; } o;
#pragma unroll
        for (int j = 0; j < 4; ++j) {
            o.us[j]     = f2bf(Ws[(size_t)(k + j) * HD + nn]);
            o.us[4 + j] = f2bf(Ws[(size_t)(k + 16 + j) * HD + nn]);
        }
        Wf1[gid] = o.u;
    } else if (bx < 2668) {
        int gid = (bx - 168) * 256 + threadIdx.x;   // 640000
        int lane = gid & 63, frag = gid >> 6;       // 0..9999
        int ks = frag % 40, rt = frag / 40;
        int row = rt * 16 + (lane & 15);
        int kb = ks * 32 + (lane >> 4) * 4;
        float4 a0 = *reinterpret_cast<const float4*>(xt + (size_t)row * DT + kb);
        float4 a1 = *reinterpret_cast<const float4*>(xt + (size_t)row * DT + kb + 16);
        union { ushort us[8]; uint4 u; } o;
        o.us[0] = f2bf(a0.x); o.us[1] = f2bf(a0.y); o.us[2] = f2bf(a0.z); o.us[3] = f2bf(a0.w);
        o.us[4] = f2bf(a1.x); o.us[5] = f2bf(a1.y); o.us[6] = f2bf(a1.z); o.us[7] = f2bf(a1.w);
        xtf[gid] = o.u;
    } else if (bx < 2770) {
        int i = (bx - 2668) * 256 + threadIdx.x;
        if (i < 26000) cntz[i] = make_int4(0, 0, 0, 0);
    } else {
        int gid = (bx - 2770) * 256 + threadIdx.x;  // 4096
        int lane = gid & 63, frag = gid >> 6;       // 0..63
        int ks = frag >> 4, nct = frag & 15;
        int l15 = lane & 15, g = lane >> 4;
        int k = ks * 32 + g * 4, n = nct * 16 + l15;
        const float* Ws = (n < HD) ? W2a : W2b;
        int nn = n & 127;
        union { ushort us[8]; uint4 u; } o;
#pragma unroll
        for (int j = 0; j < 4; ++j) {
            o.us[j]     = f2bf(Ws[(size_t)(k + j) * HD + nn]);
            o.us[4 + j] = f2bf(Ws[(size_t)(k + 16 + j) * HD + nn]);
        }
        Wf2[gid] = o.u;
    }
}

// ---------------------------------------------------------------------------
// K1: build adjacency buckets (int atomics only).
// ---------------------------------------------------------------------------
__global__ __launch_bounds__(256) void k_fill(
    const int* __restrict__ src, const int* __restrict__ dst,
    int* __restrict__ cnt_src, int* __restrict__ cnt_dst,
    int* __restrict__ bsrc, int* __restrict__ bdst)
{
    int e = blockIdx.x * 256 + threadIdx.x;
    if (e >= NEDGE) return;
    int s = src[e], d = dst[e];
    int ps = atomicAdd(&cnt_src[s], 1);
    if (ps < CAP_L) bsrc[(size_t)s * CAP_L + ps] = d;
    int pd = atomicAdd(&cnt_dst[d], 1);
    if (pd < CAP_T) bdst[(size_t)d * CAP_T + pd] = s;
}

// ---------------------------------------------------------------------------
// K2: fused target pipeline, 512 threads (8 waves).
//   y_t1 / y_t2 now leave as bf16 CHUNK-ordered rows ([N_TGT][16] uint4)
//   via LDS transpose; htW2r stays f32 row-major (k_pt reads it directly).
// ---------------------------------------------------------------------------
__global__ __launch_bounds__(512) void k_tgt1m(
    const uint4* __restrict__ xtf,    // [250*40][64] bf16 A-frags
    const uint4* __restrict__ Wf1,    // [640][64] bf16 B-frags
    const uint4* __restrict__ Wf2,    // [64][64] bf16 B-frags (conv2)
    const float* __restrict__ xl,
    const int* __restrict__ bdst, const int* __restrict__ cnt_dst,
    const float* __restrict__ W1lt_l, // [4,128]
    const float* __restrict__ b1lt,
    uint4* __restrict__ y1c,          // [N_TGT][16] chunk-ordered bf16
    uint4* __restrict__ y2c,          // [N_TGT][16] chunk-ordered bf16
    float* __restrict__ htW2r)
{
    __shared__ float  ms[16][4];
    __shared__ ushort hts[16][136];
    __shared__ ushort yt1s[16][136];
    __shared__ ushort yt2s[16][136];

    int w = threadIdx.x >> 6;         // 0..7
    int lane = threadIdx.x & 63;
    int l15 = lane & 15, g = lane >> 4;
    int rt = blockIdx.x;
    int row0 = rt * 16;

    // phase A: neighbor mean of x_l
    if (threadIdx.x < 128) {
        int r = threadIdx.x >> 3, lane8 = threadIdx.x & 7;
        int row = row0 + r;
        int deg = cnt_dst[row];
        int n = min(deg, CAP_T);
        float4 acc = make_float4(0.f, 0.f, 0.f, 0.f);
        for (int i = lane8; i < n; i += 8) {
            int sid = bdst[(size_t)row * CAP_T + i];
            float4 x = *reinterpret_cast<const float4*>(xl + 4ull * (unsigned)sid);
            acc.x += x.x; acc.y += x.y; acc.z += x.z; acc.w += x.w;
        }
#pragma unroll
        for (int off = 1; off < 8; off <<= 1) {
            acc.x += __shfl_xor(acc.x, off); acc.y += __shfl_xor(acc.y, off);
            acc.z += __shfl_xor(acc.z, off); acc.w += __shfl_xor(acc.w, off);
        }
        if (lane8 == 0) {
            float dinv = 1.0f / fmaxf((float)deg, 1.0f);
            ms[r][0] = acc.x * dinv; ms[r][1] = acc.y * dinv;
            ms[r][2] = acc.z * dinv; ms[r][3] = acc.w * dinv;
        }
    }

    // phase B: conv1 MFMA K-loop
    f32x4 acc[2];
#pragma unroll
    for (int ct = 0; ct < 2; ++ct) acc[ct] = (f32x4){0.f, 0.f, 0.f, 0.f};

    for (int ks = 0; ks < DT / 32; ++ks) {
        union { uint4 u; short8v s; } ua;
        ua.u = xtf[(size_t)(rt * 40 + ks) * 64 + lane];
#pragma unroll
        for (int ct = 0; ct < 2; ++ct) {
            union { uint4 u; short8v s; } ub;
            ub.u = Wf1[(size_t)(ks * 16 + w * 2 + ct) * 64 + lane];
            acc[ct] = __builtin_amdgcn_mfma_f32_16x16x32_bf16(ua.s, ub.s, acc[ct], 0, 0, 0);
        }
    }

    __syncthreads();

    // phase C: h_t -> hts (waves 0-3); y_t1 -> yt1s (waves 4-7), LDS bf16
    if (w < 4) {
#pragma unroll
        for (int ct = 0; ct < 2; ++ct) {
            int c = w * 32 + ct * 16 + l15;
            float wl0 = W1lt_l[c], wl1 = W1lt_l[HD + c],
                  wl2 = W1lt_l[2 * HD + c], wl3 = W1lt_l[3 * HD + c];
            float bb = b1lt[c];
#pragma unroll
            for (int j = 0; j < 4; ++j) {
                int r = 4 * g + j;
                float v = acc[ct][j] + bb + ms[r][0] * wl0 + ms[r][1] * wl1
                        + ms[r][2] * wl2 + ms[r][3] * wl3;
                hts[r][c] = f2bf(fmaxf(v, 0.0f));
            }
        }
    } else {
#pragma unroll
        for (int ct = 0; ct < 2; ++ct) {
            int c = (w - 4) * 32 + ct * 16 + l15;
#pragma unroll
            for (int j = 0; j < 4; ++j) {
                yt1s[4 * g + j][c] = f2bf(acc[ct][j]);
            }
        }
    }
    __syncthreads();

    // phase D: conv2 MFMA (K=128) from LDS h_t
    f32x4 acc2[2];
#pragma unroll
    for (int ct = 0; ct < 2; ++ct) acc2[ct] = (f32x4){0.f, 0.f, 0.f, 0.f};

#pragma unroll
    for (int ks2 = 0; ks2 < 4; ++ks2) {
        int kb2 = ks2 * 32 + g * 4;
        union { ushort us[8]; short8v s; } ua2;
        *reinterpret_cast<ushort4*>(&ua2.us[0]) =
            *reinterpret_cast<const ushort4*>(&hts[l15][kb2]);
        *reinterpret_cast<ushort4*>(&ua2.us[4]) =
            *reinterpret_cast<const ushort4*>(&hts[l15][kb2 + 16]);
#pragma unroll
        for (int ct = 0; ct < 2; ++ct) {
            union { uint4 u; short8v s; } ub2;
            ub2.u = Wf2[(size_t)(ks2 * 16 + w * 2 + ct) * 64 + lane];
            acc2[ct] = __builtin_amdgcn_mfma_f32_16x16x32_bf16(ua2.s, ub2.s, acc2[ct], 0, 0, 0);
        }
    }

    if (w < 4) {
#pragma unroll
        for (int ct = 0; ct < 2; ++ct) {
            int c = w * 32 + ct * 16 + l15;
#pragma unroll
            for (int j = 0; j < 4; ++j) {
                yt2s[4 * g + j][c] = f2bf(acc2[ct][j]);
            }
        }
    } else {
#pragma unroll
        for (int ct = 0; ct < 2; ++ct) {
            int c = (w - 4) * 32 + ct * 16 + l15;
#pragma unroll
            for (int j = 0; j < 4; ++j) {
                int grow = row0 + 4 * g + j;
                htW2r[(size_t)grow * HD + c] = acc2[ct][j];
            }
        }
    }
    __syncthreads();

    // assembly: chunk-ordered uint4 stores of y_t1 / y_t2
    if (threadIdx.x < 256) {
        int nd = threadIdx.x >> 4, tc = threadIdx.x & 15;
        int ksq = tc >> 2, gg = tc & 3;
        int kb = ksq * 32 + gg * 4;
        union { ushort us[8]; uint4 u; } o1, o2;
#pragma unroll
        for (int j = 0; j < 4; ++j) {
            o1.us[j]     = yt1s[nd][kb + j];
            o1.us[4 + j] = yt1s[nd][kb + 16 + j];
            o2.us[j]     = yt2s[nd][kb + j];
            o2.us[4 + j] = yt2s[nd][kb + 16 + j];
        }
        y1c[(size_t)(row0 + nd) * 16 + tc] = o1.u;
        y2c[(size_t)(row0 + nd) * 16 + tc] = o2.u;
    }
}

// ---------------------------------------------------------------------------
// K3: FUSED ligand pipeline. Phase 1: 16 thr/node, ONE bsrc walk, gathers
// now single uint4 bf16 chunk loads from y1c/y2c (halved traffic).
// Phase 2: MFMA from LDS Ah (chunk==A-frag) + Gh epilogue -> p_l.
// ---------------------------------------------------------------------------
__global__ __launch_bounds__(256) void k_hlp(
    const float* __restrict__ xl,
    const uint4* __restrict__ y1c, const uint4* __restrict__ y2c,
    const int* __restrict__ bsrc, const int* __restrict__ cnt_src,
    const float* __restrict__ W1tl_r,  // [4,128]
    const float* __restrict__ b1tl,
    const uint4* __restrict__ Wf,      // [32][64] conv2 B-frags
    const float* __restrict__ b2tl,
    const float* __restrict__ Wp,      // [256]; ligand part = Wp[0..127]
    uint4* __restrict__ hlb,           // [N_LIG][16] chunk-ordered
    float* __restrict__ p_l)
{
    __shared__ uint4 Ah[16][17];       // padded
    __shared__ uint4 Gh[16][17];
    __shared__ float plp[4][16];

    int tc = threadIdx.x & 15;
    int nd = threadIdx.x >> 4;         // local node 0..15
    int node = blockIdx.x * 16 + nd;
    int ks = tc >> 2, g = tc & 3;
    int kb = ks * 32 + g * 4;

    // ---- phase 1: gather (bf16 chunks) + conv1 epilogue ----
    {
        int deg = cnt_src[node];
        int n = min(deg, CAP_L);
        float s[8], t[8];
#pragma unroll
        for (int j = 0; j < 8; ++j) { s[j] = 0.f; t[j] = 0.f; }
        for (int i = 0; i < n; ++i) {
            int did = bsrc[(size_t)node * CAP_L + i];
            union { uint4 u; ushort us[8]; } a, bq;
            a.u  = y1c[(size_t)did * 16 + tc];
            bq.u = y2c[(size_t)did * 16 + tc];
#pragma unroll
            for (int j = 0; j < 8; ++j) {
                s[j] += bf2f(a.us[j]);
                t[j] += bf2f(bq.us[j]);
            }
        }
        float dinv = 1.0f / fmaxf((float)deg, 1.0f);
        float4 x = *reinterpret_cast<const float4*>(xl + 4ull * (unsigned)node);

        float4 b0 = *reinterpret_cast<const float4*>(b1tl + kb);
        float4 b1 = *reinterpret_cast<const float4*>(b1tl + kb + 16);
        float4 wa0 = *reinterpret_cast<const float4*>(W1tl_r + 0 * HD + kb);
        float4 wa1 = *reinterpret_cast<const float4*>(W1tl_r + 1 * HD + kb);
        float4 wa2 = *reinterpret_cast<const float4*>(W1tl_r + 2 * HD + kb);
        float4 wa3 = *reinterpret_cast<const float4*>(W1tl_r + 3 * HD + kb);
        float4 wb0 = *reinterpret_cast<const float4*>(W1tl_r + 0 * HD + kb + 16);
        float4 wb1 = *reinterpret_cast<const float4*>(W1tl_r + 1 * HD + kb + 16);
        float4 wb2 = *reinterpret_cast<const float4*>(W1tl_r + 2 * HD + kb + 16);
        float4 wb3 = *reinterpret_cast<const float4*>(W1tl_r + 3 * HD + kb + 16);

        union { ushort us[8]; uint4 u; } o;
        o.us[0] = f2bf(fmaxf(s[0] * dinv + b0.x + x.x * wa0.x + x.y * wa1.x + x.z * wa2.x + x.w * wa3.x, 0.f));
        o.us[1] = f2bf(fmaxf(s[1] * dinv + b0.y + x.x * wa0.y + x.y * wa1.y + x.z * wa2.y + x.w * wa3.y, 0.f));
        o.us[2] = f2bf(fmaxf(s[2] * dinv + b0.z + x.x * wa0.z + x.y * wa1.z + x.z * wa2.z + x.w * wa3.z, 0.f));
        o.us[3] = f2bf(fmaxf(s[3] * dinv + b0.w + x.x * wa0.w + x.y * wa1.w + x.z * wa2.w + x.w * wa3.w, 0.f));
        o.us[4] = f2bf(fmaxf(s[4] * dinv + b1.x + x.x * wb0.x + x.y * wb1.x + x.z * wb2.x + x.w * wb3.x, 0.f));
        o.us[5] = f2bf(fmaxf(s[5] * dinv + b1.y + x.x * wb0.y + x.y * wb1.y + x.z * wb2.y + x.w * wb3.y, 0.f));
        o.us[6] = f2bf(fmaxf(s[6] * dinv + b1.z + x.x * wb0.z + x.y * wb1.z + x.z * wb2.z + x.w * wb3.z, 0.f));
        o.us[7] = f2bf(fmaxf(s[7] * dinv + b1.w + x.x * wb0.w + x.y * wb1.w + x.z * wb2.w + x.w * wb3.w, 0.f));
        hlb[(size_t)node * 16 + tc] = o.u;
        Ah[nd][tc] = o.u;

        union { ushort us[8]; uint4 u; } q;
#pragma unroll
        for (int j = 0; j < 8; ++j) q.us[j] = f2bf(t[j] * dinv);
        Gh[nd][tc] = q.u;
    }
    __syncthreads();

    // ---- phase 2: MFMA + predictor ----
    int w = threadIdx.x >> 6;          // wave 0..3, owns ct = 2w, 2w+1
    int lane = threadIdx.x & 63;
    int l15 = lane & 15, gq = lane >> 4;

    f32x4 acc[2];
#pragma unroll
    for (int c2 = 0; c2 < 2; ++c2) acc[c2] = (f32x4){0.f, 0.f, 0.f, 0.f};

#pragma unroll
    for (int ksq = 0; ksq < 4; ++ksq) {
        union { uint4 u; short8v s; } ua;
        ua.u = Ah[l15][ksq * 4 + gq];
#pragma unroll
        for (int c2 = 0; c2 < 2; ++c2) {
            int ct = w * 2 + c2;
            union { uint4 u; short8v s; } ub;
            ub.u = Wf[(ksq * 8 + ct) * 64 + lane];
            acc[c2] = __builtin_amdgcn_mfma_f32_16x16x32_bf16(ua.s, ub.s, acc[c2], 0, 0, 0);
        }
    }

    float wpv[2], bv[2];
    int off8[2];
#pragma unroll
    for (int c2 = 0; c2 < 2; ++c2) {
        int ct = w * 2 + c2;
        int c = ct * 16 + l15;
        wpv[c2] = Wp[c];
        bv[c2]  = b2tl[c];
        off8[c2] = (((ct >> 1) * 4 + (l15 >> 2)) << 3) + ((ct & 1) << 2) + (l15 & 3);
    }

#pragma unroll
    for (int j = 0; j < 4; ++j) {
        int r = gq * 4 + j;
        const ushort* gp = reinterpret_cast<const ushort*>(&Gh[r][0]);
        float part = 0.f;
#pragma unroll
        for (int c2 = 0; c2 < 2; ++c2) {
            float v = acc[c2][j] + bf2f(gp[off8[c2]]) + bv[c2];
            part += fmaxf(v, 0.f) * wpv[c2];
        }
#pragma unroll
        for (int off = 1; off < 16; off <<= 1) part += __shfl_xor(part, off);
        if (l15 == 0) plp[w][r] = part;
    }
    __syncthreads();

    if (threadIdx.x < 16) {
        int r = threadIdx.x;
        p_l[blockIdx.x * 16 + r] = plp[0][r] + plp[1][r] + plp[2][r] + plp[3][r];
    }
}

// ---------------------------------------------------------------------------
// K5: target predictor (LDS-staged indices, 16x16 uint4 gather from
// chunk-ordered hlb, un-permute in msh phase — verified).
// ---------------------------------------------------------------------------
__global__ __launch_bounds__(256) void k_pt(
    const uint4* __restrict__ hlb,    // chunk-ordered
    const int* __restrict__ bdst, const int* __restrict__ cnt_dst,
    const float* __restrict__ Wlt,    // W2lt_l [128,128]
    const float* __restrict__ b2lt,
    const float* __restrict__ htW2r,
    const float* __restrict__ Wp,     // [256]
    float* __restrict__ p_t)
{
    __shared__ int   idx[CAP_T];
    __shared__ float sm[16][132];
    __shared__ float msh[HD];
    __shared__ float sum2[2];

    int row = blockIdx.x;
    int deg = cnt_dst[row];
    int nn = min(deg, CAP_T);

    if (threadIdx.x < CAP_T) idx[threadIdx.x] = bdst[(size_t)row * CAP_T + threadIdx.x];
    __syncthreads();

    int wg = threadIdx.x >> 4, l16 = threadIdx.x & 15;
    float s[8];
#pragma unroll
    for (int j = 0; j < 8; ++j) s[j] = 0.f;
    for (int i = wg; i < nn; i += 16) {
        int sid = idx[i];
        union { uint4 u; ushort us[8]; } v;
        v.u = hlb[(size_t)sid * 16 + l16];
#pragma unroll
        for (int j = 0; j < 8; ++j) s[j] += bf2f(v.us[j]);
    }
#pragma unroll
    for (int j = 0; j < 8; ++j) sm[wg][l16 * 8 + j] = s[j];
    __syncthreads();

    if (threadIdx.x < HD) {
        int h = threadIdx.x;
        int tc2 = h >> 3, jj = h & 7;
        float dinv = 1.0f / fmaxf((float)deg, 1.0f);
        float acc = 0.f;
#pragma unroll
        for (int w2 = 0; w2 < 16; ++w2) acc += sm[w2][tc2 * 8 + jj];
        int ks2 = tc2 >> 2, g2 = tc2 & 3;
        int col = ks2 * 32 + ((jj >> 2) << 4) + g2 * 4 + (jj & 3);
        msh[col] = acc * dinv;
    }
    __syncthreads();

    if (threadIdx.x < HD) {
        int h = threadIdx.x;
        float g = 0.f;
        for (int k = 0; k < HD; k += 4) {
            float4 mk = *reinterpret_cast<const float4*>(&msh[k]);
            g += mk.x * Wlt[(size_t)(k + 0) * HD + h] + mk.y * Wlt[(size_t)(k + 1) * HD + h]
               + mk.z * Wlt[(size_t)(k + 2) * HD + h] + mk.w * Wlt[(size_t)(k + 3) * HD + h];
        }
        float v = fmaxf(g + b2lt[h] + htW2r[(size_t)row * HD + h], 0.0f);
        float part = v * Wp[HD + h];
#pragma unroll
        for (int off = 1; off < 64; off <<= 1) part += __shfl_xor(part, off);
        if ((h & 63) == 0) sum2[h >> 6] = part;
    }
    __syncthreads();
    if (threadIdx.x == 0) p_t[row] = sum2[0] + sum2[1];
}

// ---------------------------------------------------------------------------
// K7: out[e] = p_l[src[e]] + p_t[dst[e]] + bp
// ---------------------------------------------------------------------------
__global__ __launch_bounds__(256) void k_out(
    const int* __restrict__ src, const int* __restrict__ dst,
    const float* __restrict__ p_l, const float* __restrict__ p_t,
    const float* __restrict__ bp, float* __restrict__ out)
{
    int e = blockIdx.x * 256 + threadIdx.x;
    if (e >= NEDGE) return;
    out[e] = p_l[src[e]] + p_t[dst[e]] + bp[0];
}

// ---------------------------------------------------------------------------
extern "C" void kernel_launch(void* const* d_in, const int* in_sizes, int n_in,
                              void* d_out, int out_size, void* d_ws, size_t ws_size,
                              hipStream_t stream)
{
    const float* x_l    = (const float*)d_in[0];
    const float* x_t    = (const float*)d_in[1];
    const int*   ei     = (const int*)  d_in[2];
    const float* W1lt_l = (const float*)d_in[3];
    const float* b1lt   = (const float*)d_in[4];
    const float* W1lt_r = (const float*)d_in[5];
    const float* W1tl_l = (const float*)d_in[6];
    const float* b1tl   = (const float*)d_in[7];
    const float* W1tl_r = (const float*)d_in[8];
    const float* W2lt_l = (const float*)d_in[9];
    const float* b2lt   = (const float*)d_in[10];
    const float* W2lt_r = (const float*)d_in[11];
    const float* W2tl_l = (const float*)d_in[12];
    const float* b2tl   = (const float*)d_in[13];
    const float* W2tl_r = (const float*)d_in[14];
    const float* Wp     = (const float*)d_in[15];
    const float* bp     = (const float*)d_in[16];

    const int* src = ei;            // ligand indices
    const int* dst = ei + NEDGE;    // target indices

    char* ws = (char*)d_ws;
    size_t o = 0;
    int* cnt_src = (int*)(ws + o); o += (size_t)N_LIG * 4;
    int* cnt_dst = (int*)(ws + o); o += (size_t)N_TGT * 4;
    int* bsrc = (int*)(ws + o); o += (size_t)N_LIG * CAP_L * 4;
    int* bdst = (int*)(ws + o); o += (size_t)N_TGT * CAP_T * 4;
    uint4* hlb   = (uint4*)(ws + o);  o += (size_t)N_LIG * HD * 2;
    uint4* y1c   = (uint4*)(ws + o);  o += (size_t)N_TGT * 16 * 16;
    uint4* y2c   = (uint4*)(ws + o);  o += (size_t)N_TGT * 16 * 16;
    uint4* Wf    = (uint4*)(ws + o);  o += (size_t)32 * 64 * 16;
    uint4* Wf1   = (uint4*)(ws + o);  o += (size_t)640 * 64 * 16;
    uint4* Wf2   = (uint4*)(ws + o);  o += (size_t)64 * 64 * 16;
    uint4* xtf   = (uint4*)(ws + o);  o += (size_t)10000 * 64 * 16;
    float* htW2r = (float*)(ws + o); o += (size_t)N_TGT * HD * 4;
    float* p_l   = (float*)(ws + o); o += (size_t)N_LIG * 4;
    float* p_t   = (float*)(ws + o); o += (size_t)N_TGT * 4;

    float* out = (float*)d_out;

    // merged prep: fragment packing (incl. conv2 weights) + counter zeroing
    k_pack<<<2786, 256, 0, stream>>>(W2tl_r, Wf, W1lt_r, W1tl_l, Wf1,
                                     x_t, xtf, (int4*)cnt_src,
                                     W2tl_l, W2lt_r, Wf2);

    k_fill<<<(NEDGE + 255) / 256, 256, 0, stream>>>(src, dst, cnt_src, cnt_dst, bsrc, bdst);

    // fused target pipeline: conv1 + neighbor-mean + conv2 projections
    k_tgt1m<<<N_TGT / 16, 512, 0, stream>>>(xtf, Wf1, Wf2, x_l, bdst, cnt_dst,
                                            W1lt_l, b1lt, y1c, y2c, htW2r);

    // fused ligand pipeline: conv1 gather + conv2 MFMA + predictor
    k_hlp<<<NTILE_L, 256, 0, stream>>>(x_l, y1c, y2c, bsrc, cnt_src,
                                       W1tl_r, b1tl, Wf, b2tl, Wp, hlb, p_l);

    // target predictor
    k_pt<<<N_TGT, 256, 0, stream>>>(hlb, bdst, cnt_dst,
                                    W2lt_l, b2lt, htW2r, Wp, p_t);

    // edges
    k_out<<<(NEDGE + 255) / 256, 256, 0, stream>>>(src, dst, p_l, p_t, bp, out);
}

// Round 21
// 95.027 us; speedup vs baseline: 1.3834x; 1.0089x over previous
//
#include <hip/hip_runtime.h>
#include <hip/hip_bf16.h>

#define N_LIG 100000
#define N_TGT 4000
#define NEDGE 150000
#define DT 1280
#define HD 128
#define CAP_L 32
#define CAP_T 128
#define NTILE_L 6250            // N_LIG / 16

typedef __attribute__((ext_vector_type(8))) short short8v;
typedef __attribute__((ext_vector_type(4))) float f32x4;

static __device__ __forceinline__ ushort f2bf(float f) {
    __hip_bfloat16 h = __float2bfloat16(f);
    union { __hip_bfloat16 h; ushort u; } c; c.h = h; return c.u;
}
static __device__ __forceinline__ float bf2f(ushort u) {
    union { unsigned v; float f; } c; c.v = ((unsigned)u) << 16; return c.f;
}

// ---------------------------------------------------------------------------
// K0: merged prep — fragment packing for all MFMA operands + counter zeroing.
// ---------------------------------------------------------------------------
__global__ __launch_bounds__(256) void k_pack(
    const float* __restrict__ W2, uint4* __restrict__ Wf,
    const float* __restrict__ Wr, const float* __restrict__ Wl,
    uint4* __restrict__ Wf1,
    const float* __restrict__ xt, uint4* __restrict__ xtf,
    int4* __restrict__ cntz,
    const float* __restrict__ W2a, const float* __restrict__ W2b,
    uint4* __restrict__ Wf2)
{
    int bx = blockIdx.x;
    if (bx < 8) {
        int gid = bx * 256 + threadIdx.x;           // 2048
        int lane = gid & 63, frag = gid >> 6;       // frag 0..31
        int ks = frag >> 3, ct = frag & 7;
        int l15 = lane & 15, g = lane >> 4;
        int k = ks * 32 + g * 4, n = ct * 16 + l15;
        union { ushort us[8]; uint4 u; } o;
#pragma unroll
        for (int j = 0; j < 4; ++j) {
            o.us[j]     = f2bf(W2[(size_t)(k + j) * HD + n]);
            o.us[4 + j] = f2bf(W2[(size_t)(k + 16 + j) * HD + n]);
        }
        Wf[gid] = o.u;
    } else if (bx < 168) {
        int gid = (bx - 8) * 256 + threadIdx.x;     // 40960
        int lane = gid & 63, frag = gid >> 6;       // 0..639
        int ks = frag >> 4, nct = frag & 15;
        int l15 = lane & 15, g = lane >> 4;
        int k = ks * 32 + g * 4, n = nct * 16 + l15;
        const float* Ws = (n < HD) ? Wr : Wl;
        int nn = n & 127;
        union { ushort us[8]; uint4 u; } o;
#pragma unroll
        for (int j = 0; j < 4; ++j) {
            o.us[j]     = f2bf(Ws[(size_t)(k + j) * HD + nn]);
            o.us[4 + j] = f2bf(Ws[(size_t)(k + 16 + j) * HD + nn]);
        }
        Wf1[gid] = o.u;
    } else if (bx < 2668) {
        int gid = (bx - 168) * 256 + threadIdx.x;   // 640000
        int lane = gid & 63, frag = gid >> 6;       // 0..9999
        int ks = frag % 40, rt = frag / 40;
        int row = rt * 16 + (lane & 15);
        int kb = ks * 32 + (lane >> 4) * 4;
        float4 a0 = *reinterpret_cast<const float4*>(xt + (size_t)row * DT + kb);
        float4 a1 = *reinterpret_cast<const float4*>(xt + (size_t)row * DT + kb + 16);
        union { ushort us[8]; uint4 u; } o;
        o.us[0] = f2bf(a0.x); o.us[1] = f2bf(a0.y); o.us[2] = f2bf(a0.z); o.us[3] = f2bf(a0.w);
        o.us[4] = f2bf(a1.x); o.us[5] = f2bf(a1.y); o.us[6] = f2bf(a1.z); o.us[7] = f2bf(a1.w);
        xtf[gid] = o.u;
    } else if (bx < 2770) {
        int i = (bx - 2668) * 256 + threadIdx.x;
        if (i < 26000) cntz[i] = make_int4(0, 0, 0, 0);
    } else {
        int gid = (bx - 2770) * 256 + threadIdx.x;  // 4096
        int lane = gid & 63, frag = gid >> 6;       // 0..63
        int ks = frag >> 4, nct = frag & 15;
        int l15 = lane & 15, g = lane >> 4;
        int k = ks * 32 + g * 4, n = nct * 16 + l15;
        const float* Ws = (n < HD) ? W2a : W2b;
        int nn = n & 127;
        union { ushort us[8]; uint4 u; } o;
#pragma unroll
        for (int j = 0; j < 4; ++j) {
            o.us[j]     = f2bf(Ws[(size_t)(k + j) * HD + nn]);
            o.us[4 + j] = f2bf(Ws[(size_t)(k + 16 + j) * HD + nn]);
        }
        Wf2[gid] = o.u;
    }
}

// ---------------------------------------------------------------------------
// K1: build adjacency buckets (int atomics only) + per-edge id in dst bucket.
// ---------------------------------------------------------------------------
__global__ __launch_bounds__(256) void k_fill(
    const int* __restrict__ src, const int* __restrict__ dst,
    int* __restrict__ cnt_src, int* __restrict__ cnt_dst,
    int* __restrict__ bsrc, int* __restrict__ bdst, int* __restrict__ ebid)
{
    int e = blockIdx.x * 256 + threadIdx.x;
    if (e >= NEDGE) return;
    int s = src[e], d = dst[e];
    int ps = atomicAdd(&cnt_src[s], 1);
    if (ps < CAP_L) bsrc[(size_t)s * CAP_L + ps] = d;
    int pd = atomicAdd(&cnt_dst[d], 1);
    if (pd < CAP_T) {
        bdst[(size_t)d * CAP_T + pd] = s;
        ebid[(size_t)d * CAP_T + pd] = e;
    }
}

// ---------------------------------------------------------------------------
// K2: fused target pipeline, 512 threads (8 waves).
//   y_t1 / y_t2 leave as bf16 CHUNK-ordered rows ([N_TGT][16] uint4);
//   htW2r stays f32 row-major.
// ---------------------------------------------------------------------------
__global__ __launch_bounds__(512) void k_tgt1m(
    const uint4* __restrict__ xtf,    // [250*40][64] bf16 A-frags
    const uint4* __restrict__ Wf1,    // [640][64] bf16 B-frags
    const uint4* __restrict__ Wf2,    // [64][64] bf16 B-frags (conv2)
    const float* __restrict__ xl,
    const int* __restrict__ bdst, const int* __restrict__ cnt_dst,
    const float* __restrict__ W1lt_l, // [4,128]
    const float* __restrict__ b1lt,
    uint4* __restrict__ y1c,          // [N_TGT][16] chunk-ordered bf16
    uint4* __restrict__ y2c,          // [N_TGT][16] chunk-ordered bf16
    float* __restrict__ htW2r)
{
    __shared__ float  ms[16][4];
    __shared__ ushort hts[16][136];
    __shared__ ushort yt1s[16][136];
    __shared__ ushort yt2s[16][136];

    int w = threadIdx.x >> 6;         // 0..7
    int lane = threadIdx.x & 63;
    int l15 = lane & 15, g = lane >> 4;
    int rt = blockIdx.x;
    int row0 = rt * 16;

    // phase A: neighbor mean of x_l
    if (threadIdx.x < 128) {
        int r = threadIdx.x >> 3, lane8 = threadIdx.x & 7;
        int row = row0 + r;
        int deg = cnt_dst[row];
        int n = min(deg, CAP_T);
        float4 acc = make_float4(0.f, 0.f, 0.f, 0.f);
        for (int i = lane8; i < n; i += 8) {
            int sid = bdst[(size_t)row * CAP_T + i];
            float4 x = *reinterpret_cast<const float4*>(xl + 4ull * (unsigned)sid);
            acc.x += x.x; acc.y += x.y; acc.z += x.z; acc.w += x.w;
        }
#pragma unroll
        for (int off = 1; off < 8; off <<= 1) {
            acc.x += __shfl_xor(acc.x, off); acc.y += __shfl_xor(acc.y, off);
            acc.z += __shfl_xor(acc.z, off); acc.w += __shfl_xor(acc.w, off);
        }
        if (lane8 == 0) {
            float dinv = 1.0f / fmaxf((float)deg, 1.0f);
            ms[r][0] = acc.x * dinv; ms[r][1] = acc.y * dinv;
            ms[r][2] = acc.z * dinv; ms[r][3] = acc.w * dinv;
        }
    }

    // phase B: conv1 MFMA K-loop
    f32x4 acc[2];
#pragma unroll
    for (int ct = 0; ct < 2; ++ct) acc[ct] = (f32x4){0.f, 0.f, 0.f, 0.f};

    for (int ks = 0; ks < DT / 32; ++ks) {
        union { uint4 u; short8v s; } ua;
        ua.u = xtf[(size_t)(rt * 40 + ks) * 64 + lane];
#pragma unroll
        for (int ct = 0; ct < 2; ++ct) {
            union { uint4 u; short8v s; } ub;
            ub.u = Wf1[(size_t)(ks * 16 + w * 2 + ct) * 64 + lane];
            acc[ct] = __builtin_amdgcn_mfma_f32_16x16x32_bf16(ua.s, ub.s, acc[ct], 0, 0, 0);
        }
    }

    __syncthreads();

    // phase C: h_t -> hts (waves 0-3); y_t1 -> yt1s (waves 4-7), LDS bf16
    if (w < 4) {
#pragma unroll
        for (int ct = 0; ct < 2; ++ct) {
            int c = w * 32 + ct * 16 + l15;
            float wl0 = W1lt_l[c], wl1 = W1lt_l[HD + c],
                  wl2 = W1lt_l[2 * HD + c], wl3 = W1lt_l[3 * HD + c];
            float bb = b1lt[c];
#pragma unroll
            for (int j = 0; j < 4; ++j) {
                int r = 4 * g + j;
                float v = acc[ct][j] + bb + ms[r][0] * wl0 + ms[r][1] * wl1
                        + ms[r][2] * wl2 + ms[r][3] * wl3;
                hts[r][c] = f2bf(fmaxf(v, 0.0f));
            }
        }
    } else {
#pragma unroll
        for (int ct = 0; ct < 2; ++ct) {
            int c = (w - 4) * 32 + ct * 16 + l15;
#pragma unroll
            for (int j = 0; j < 4; ++j) {
                yt1s[4 * g + j][c] = f2bf(acc[ct][j]);
            }
        }
    }
    __syncthreads();

    // phase D: conv2 MFMA (K=128) from LDS h_t
    f32x4 acc2[2];
#pragma unroll
    for (int ct = 0; ct < 2; ++ct) acc2[ct] = (f32x4){0.f, 0.f, 0.f, 0.f};

#pragma unroll
    for (int ks2 = 0; ks2 < 4; ++ks2) {
        int kb2 = ks2 * 32 + g * 4;
        union { ushort us[8]; short8v s; } ua2;
        *reinterpret_cast<ushort4*>(&ua2.us[0]) =
            *reinterpret_cast<const ushort4*>(&hts[l15][kb2]);
        *reinterpret_cast<ushort4*>(&ua2.us[4]) =
            *reinterpret_cast<const ushort4*>(&hts[l15][kb2 + 16]);
#pragma unroll
        for (int ct = 0; ct < 2; ++ct) {
            union { uint4 u; short8v s; } ub2;
            ub2.u = Wf2[(size_t)(ks2 * 16 + w * 2 + ct) * 64 + lane];
            acc2[ct] = __builtin_amdgcn_mfma_f32_16x16x32_bf16(ua2.s, ub2.s, acc2[ct], 0, 0, 0);
        }
    }

    if (w < 4) {
#pragma unroll
        for (int ct = 0; ct < 2; ++ct) {
            int c = w * 32 + ct * 16 + l15;
#pragma unroll
            for (int j = 0; j < 4; ++j) {
                yt2s[4 * g + j][c] = f2bf(acc2[ct][j]);
            }
        }
    } else {
#pragma unroll
        for (int ct = 0; ct < 2; ++ct) {
            int c = (w - 4) * 32 + ct * 16 + l15;
#pragma unroll
            for (int j = 0; j < 4; ++j) {
                int grow = row0 + 4 * g + j;
                htW2r[(size_t)grow * HD + c] = acc2[ct][j];
            }
        }
    }
    __syncthreads();

    // assembly: chunk-ordered uint4 stores of y_t1 / y_t2
    if (threadIdx.x < 256) {
        int nd = threadIdx.x >> 4, tc = threadIdx.x & 15;
        int ksq = tc >> 2, gg = tc & 3;
        int kb = ksq * 32 + gg * 4;
        union { ushort us[8]; uint4 u; } o1, o2;
#pragma unroll
        for (int j = 0; j < 4; ++j) {
            o1.us[j]     = yt1s[nd][kb + j];
            o1.us[4 + j] = yt1s[nd][kb + 16 + j];
            o2.us[j]     = yt2s[nd][kb + j];
            o2.us[4 + j] = yt2s[nd][kb + 16 + j];
        }
        y1c[(size_t)(row0 + nd) * 16 + tc] = o1.u;
        y2c[(size_t)(row0 + nd) * 16 + tc] = o2.u;
    }
}

// ---------------------------------------------------------------------------
// K3: FUSED ligand pipeline. Phase 1: 16 thr/node, ONE bsrc walk, single
// uint4 bf16 chunk loads from y1c/y2c. Phase 2: MFMA from LDS Ah + Gh
// epilogue -> p_l.
// ---------------------------------------------------------------------------
__global__ __launch_bounds__(256) void k_hlp(
    const float* __restrict__ xl,
    const uint4* __restrict__ y1c, const uint4* __restrict__ y2c,
    const int* __restrict__ bsrc, const int* __restrict__ cnt_src,
    const float* __restrict__ W1tl_r,  // [4,128]
    const float* __restrict__ b1tl,
    const uint4* __restrict__ Wf,      // [32][64] conv2 B-frags
    const float* __restrict__ b2tl,
    const float* __restrict__ Wp,      // [256]; ligand part = Wp[0..127]
    uint4* __restrict__ hlb,           // [N_LIG][16] chunk-ordered
    float* __restrict__ p_l)
{
    __shared__ uint4 Ah[16][17];       // padded
    __shared__ uint4 Gh[16][17];
    __shared__ float plp[4][16];

    int tc = threadIdx.x & 15;
    int nd = threadIdx.x >> 4;         // local node 0..15
    int node = blockIdx.x * 16 + nd;
    int ks = tc >> 2, g = tc & 3;
    int kb = ks * 32 + g * 4;

    // ---- phase 1: gather (bf16 chunks) + conv1 epilogue ----
    {
        int deg = cnt_src[node];
        int n = min(deg, CAP_L);
        float s[8], t[8];
#pragma unroll
        for (int j = 0; j < 8; ++j) { s[j] = 0.f; t[j] = 0.f; }
        for (int i = 0; i < n; ++i) {
            int did = bsrc[(size_t)node * CAP_L + i];
            union { uint4 u; ushort us[8]; } a, bq;
            a.u  = y1c[(size_t)did * 16 + tc];
            bq.u = y2c[(size_t)did * 16 + tc];
#pragma unroll
            for (int j = 0; j < 8; ++j) {
                s[j] += bf2f(a.us[j]);
                t[j] += bf2f(bq.us[j]);
            }
        }
        float dinv = 1.0f / fmaxf((float)deg, 1.0f);
        float4 x = *reinterpret_cast<const float4*>(xl + 4ull * (unsigned)node);

        float4 b0 = *reinterpret_cast<const float4*>(b1tl + kb);
        float4 b1 = *reinterpret_cast<const float4*>(b1tl + kb + 16);
        float4 wa0 = *reinterpret_cast<const float4*>(W1tl_r + 0 * HD + kb);
        float4 wa1 = *reinterpret_cast<const float4*>(W1tl_r + 1 * HD + kb);
        float4 wa2 = *reinterpret_cast<const float4*>(W1tl_r + 2 * HD + kb);
        float4 wa3 = *reinterpret_cast<const float4*>(W1tl_r + 3 * HD + kb);
        float4 wb0 = *reinterpret_cast<const float4*>(W1tl_r + 0 * HD + kb + 16);
        float4 wb1 = *reinterpret_cast<const float4*>(W1tl_r + 1 * HD + kb + 16);
        float4 wb2 = *reinterpret_cast<const float4*>(W1tl_r + 2 * HD + kb + 16);
        float4 wb3 = *reinterpret_cast<const float4*>(W1tl_r + 3 * HD + kb + 16);

        union { ushort us[8]; uint4 u; } o;
        o.us[0] = f2bf(fmaxf(s[0] * dinv + b0.x + x.x * wa0.x + x.y * wa1.x + x.z * wa2.x + x.w * wa3.x, 0.f));
        o.us[1] = f2bf(fmaxf(s[1] * dinv + b0.y + x.x * wa0.y + x.y * wa1.y + x.z * wa2.y + x.w * wa3.y, 0.f));
        o.us[2] = f2bf(fmaxf(s[2] * dinv + b0.z + x.x * wa0.z + x.y * wa1.z + x.z * wa2.z + x.w * wa3.z, 0.f));
        o.us[3] = f2bf(fmaxf(s[3] * dinv + b0.w + x.x * wa0.w + x.y * wa1.w + x.z * wa2.w + x.w * wa3.w, 0.f));
        o.us[4] = f2bf(fmaxf(s[4] * dinv + b1.x + x.x * wb0.x + x.y * wb1.x + x.z * wb2.x + x.w * wb3.x, 0.f));
        o.us[5] = f2bf(fmaxf(s[5] * dinv + b1.y + x.x * wb0.y + x.y * wb1.y + x.z * wb2.y + x.w * wb3.y, 0.f));
        o.us[6] = f2bf(fmaxf(s[6] * dinv + b1.z + x.x * wb0.z + x.y * wb1.z + x.z * wb2.z + x.w * wb3.z, 0.f));
        o.us[7] = f2bf(fmaxf(s[7] * dinv + b1.w + x.x * wb0.w + x.y * wb1.w + x.z * wb2.w + x.w * wb3.w, 0.f));
        hlb[(size_t)node * 16 + tc] = o.u;
        Ah[nd][tc] = o.u;

        union { ushort us[8]; uint4 u; } q;
#pragma unroll
        for (int j = 0; j < 8; ++j) q.us[j] = f2bf(t[j] * dinv);
        Gh[nd][tc] = q.u;
    }
    __syncthreads();

    // ---- phase 2: MFMA + predictor ----
    int w = threadIdx.x >> 6;          // wave 0..3, owns ct = 2w, 2w+1
    int lane = threadIdx.x & 63;
    int l15 = lane & 15, gq = lane >> 4;

    f32x4 acc[2];
#pragma unroll
    for (int c2 = 0; c2 < 2; ++c2) acc[c2] = (f32x4){0.f, 0.f, 0.f, 0.f};

#pragma unroll
    for (int ksq = 0; ksq < 4; ++ksq) {
        union { uint4 u; short8v s; } ua;
        ua.u = Ah[l15][ksq * 4 + gq];
#pragma unroll
        for (int c2 = 0; c2 < 2; ++c2) {
            int ct = w * 2 + c2;
            union { uint4 u; short8v s; } ub;
            ub.u = Wf[(ksq * 8 + ct) * 64 + lane];
            acc[c2] = __builtin_amdgcn_mfma_f32_16x16x32_bf16(ua.s, ub.s, acc[c2], 0, 0, 0);
        }
    }

    float wpv[2], bv[2];
    int off8[2];
#pragma unroll
    for (int c2 = 0; c2 < 2; ++c2) {
        int ct = w * 2 + c2;
        int c = ct * 16 + l15;
        wpv[c2] = Wp[c];
        bv[c2]  = b2tl[c];
        off8[c2] = (((ct >> 1) * 4 + (l15 >> 2)) << 3) + ((ct & 1) << 2) + (l15 & 3);
    }

#pragma unroll
    for (int j = 0; j < 4; ++j) {
        int r = gq * 4 + j;
        const ushort* gp = reinterpret_cast<const ushort*>(&Gh[r][0]);
        float part = 0.f;
#pragma unroll
        for (int c2 = 0; c2 < 2; ++c2) {
            float v = acc[c2][j] + bf2f(gp[off8[c2]]) + bv[c2];
            part += fmaxf(v, 0.f) * wpv[c2];
        }
#pragma unroll
        for (int off = 1; off < 16; off <<= 1) part += __shfl_xor(part, off);
        if (l15 == 0) plp[w][r] = part;
    }
    __syncthreads();

    if (threadIdx.x < 16) {
        int r = threadIdx.x;
        p_l[blockIdx.x * 16 + r] = plp[0][r] + plp[1][r] + plp[2][r] + plp[3][r];
    }
}

// ---------------------------------------------------------------------------
// K5: target predictor + FUSED edge output.
//   gather hlb chunks -> mean -> GEMM -> p_t (in LDS), then write
//   out[ebid[i]] = p_l[idx[i]] + p_t + bp for this row's edges.
// ---------------------------------------------------------------------------
__global__ __launch_bounds__(256) void k_pt(
    const uint4* __restrict__ hlb,    // chunk-ordered
    const int* __restrict__ bdst, const int* __restrict__ cnt_dst,
    const int* __restrict__ ebid,
    const float* __restrict__ Wlt,    // W2lt_l [128,128]
    const float* __restrict__ b2lt,
    const float* __restrict__ htW2r,
    const float* __restrict__ Wp,     // [256]
    const float* __restrict__ p_l,
    const float* __restrict__ bp,
    float* __restrict__ out)
{
    __shared__ int   idx[CAP_T];
    __shared__ float sm[16][132];
    __shared__ float msh[HD];
    __shared__ float sum2[2];
    __shared__ float ptv;

    int row = blockIdx.x;
    int deg = cnt_dst[row];
    int nn = min(deg, CAP_T);

    if (threadIdx.x < CAP_T) idx[threadIdx.x] = bdst[(size_t)row * CAP_T + threadIdx.x];
    __syncthreads();

    int wg = threadIdx.x >> 4, l16 = threadIdx.x & 15;
    float s[8];
#pragma unroll
    for (int j = 0; j < 8; ++j) s[j] = 0.f;
    for (int i = wg; i < nn; i += 16) {
        int sid = idx[i];
        union { uint4 u; ushort us[8]; } v;
        v.u = hlb[(size_t)sid * 16 + l16];
#pragma unroll
        for (int j = 0; j < 8; ++j) s[j] += bf2f(v.us[j]);
    }
#pragma unroll
    for (int j = 0; j < 8; ++j) sm[wg][l16 * 8 + j] = s[j];
    __syncthreads();

    if (threadIdx.x < HD) {
        int h = threadIdx.x;
        int tc2 = h >> 3, jj = h & 7;
        float dinv = 1.0f / fmaxf((float)deg, 1.0f);
        float acc = 0.f;
#pragma unroll
        for (int w2 = 0; w2 < 16; ++w2) acc += sm[w2][tc2 * 8 + jj];
        int ks2 = tc2 >> 2, g2 = tc2 & 3;
        int col = ks2 * 32 + ((jj >> 2) << 4) + g2 * 4 + (jj & 3);
        msh[col] = acc * dinv;
    }
    __syncthreads();

    if (threadIdx.x < HD) {
        int h = threadIdx.x;
        float g = 0.f;
        for (int k = 0; k < HD; k += 4) {
            float4 mk = *reinterpret_cast<const float4*>(&msh[k]);
            g += mk.x * Wlt[(size_t)(k + 0) * HD + h] + mk.y * Wlt[(size_t)(k + 1) * HD + h]
               + mk.z * Wlt[(size_t)(k + 2) * HD + h] + mk.w * Wlt[(size_t)(k + 3) * HD + h];
        }
        float v = fmaxf(g + b2lt[h] + htW2r[(size_t)row * HD + h], 0.0f);
        float part = v * Wp[HD + h];
#pragma unroll
        for (int off = 1; off < 64; off <<= 1) part += __shfl_xor(part, off);
        if ((h & 63) == 0) sum2[h >> 6] = part;
    }
    __syncthreads();
    if (threadIdx.x == 0) ptv = sum2[0] + sum2[1];
    __syncthreads();

    // fused edge output for this row's edges
    float base = ptv + bp[0];
    for (int i = threadIdx.x; i < nn; i += 256) {
        int e = ebid[(size_t)row * CAP_T + i];
        out[e] = p_l[idx[i]] + base;
    }
}

// ---------------------------------------------------------------------------
extern "C" void kernel_launch(void* const* d_in, const int* in_sizes, int n_in,
                              void* d_out, int out_size, void* d_ws, size_t ws_size,
                              hipStream_t stream)
{
    const float* x_l    = (const float*)d_in[0];
    const float* x_t    = (const float*)d_in[1];
    const int*   ei     = (const int*)  d_in[2];
    const float* W1lt_l = (const float*)d_in[3];
    const float* b1lt   = (const float*)d_in[4];
    const float* W1lt_r = (const float*)d_in[5];
    const float* W1tl_l = (const float*)d_in[6];
    const float* b1tl   = (const float*)d_in[7];
    const float* W1tl_r = (const float*)d_in[8];
    const float* W2lt_l = (const float*)d_in[9];
    const float* b2lt   = (const float*)d_in[10];
    const float* W2lt_r = (const float*)d_in[11];
    const float* W2tl_l = (const float*)d_in[12];
    const float* b2tl   = (const float*)d_in[13];
    const float* W2tl_r = (const float*)d_in[14];
    const float* Wp     = (const float*)d_in[15];
    const float* bp     = (const float*)d_in[16];

    const int* src = ei;            // ligand indices
    const int* dst = ei + NEDGE;    // target indices

    char* ws = (char*)d_ws;
    size_t o = 0;
    int* cnt_src = (int*)(ws + o); o += (size_t)N_LIG * 4;
    int* cnt_dst = (int*)(ws + o); o += (size_t)N_TGT * 4;
    int* bsrc = (int*)(ws + o); o += (size_t)N_LIG * CAP_L * 4;
    int* bdst = (int*)(ws + o); o += (size_t)N_TGT * CAP_T * 4;
    int* ebid = (int*)(ws + o); o += (size_t)N_TGT * CAP_T * 4;
    uint4* hlb   = (uint4*)(ws + o);  o += (size_t)N_LIG * HD * 2;
    uint4* y1c   = (uint4*)(ws + o);  o += (size_t)N_TGT * 16 * 16;
    uint4* y2c   = (uint4*)(ws + o);  o += (size_t)N_TGT * 16 * 16;
    uint4* Wf    = (uint4*)(ws + o);  o += (size_t)32 * 64 * 16;
    uint4* Wf1   = (uint4*)(ws + o);  o += (size_t)640 * 64 * 16;
    uint4* Wf2   = (uint4*)(ws + o);  o += (size_t)64 * 64 * 16;
    uint4* xtf   = (uint4*)(ws + o);  o += (size_t)10000 * 64 * 16;
    float* htW2r = (float*)(ws + o); o += (size_t)N_TGT * HD * 4;
    float* p_l   = (float*)(ws + o); o += (size_t)N_LIG * 4;

    float* out = (float*)d_out;

    // merged prep: fragment packing (incl. conv2 weights) + counter zeroing
    k_pack<<<2786, 256, 0, stream>>>(W2tl_r, Wf, W1lt_r, W1tl_l, Wf1,
                                     x_t, xtf, (int4*)cnt_src,
                                     W2tl_l, W2lt_r, Wf2);

    k_fill<<<(NEDGE + 255) / 256, 256, 0, stream>>>(src, dst, cnt_src, cnt_dst,
                                                    bsrc, bdst, ebid);

    // fused target pipeline: conv1 + neighbor-mean + conv2 projections
    k_tgt1m<<<N_TGT / 16, 512, 0, stream>>>(xtf, Wf1, Wf2, x_l, bdst, cnt_dst,
                                            W1lt_l, b1lt, y1c, y2c, htW2r);

    // fused ligand pipeline: conv1 gather + conv2 MFMA + predictor
    k_hlp<<<NTILE_L, 256, 0, stream>>>(x_l, y1c, y2c, bsrc, cnt_src,
                                       W1tl_r, b1tl, Wf, b2tl, Wp, hlb, p_l);

    // target predictor + fused edge output
    k_pt<<<N_TGT, 256, 0, stream>>>(hlb, bdst, cnt_dst, ebid,
                                    W2lt_l, b2lt, htW2r, Wp, p_l, bp, out);
}